// Round 3
// baseline (4737.403 us; speedup 1.0000x reference)
//
#include <hip/hip_runtime.h>

// ---------------- problem constants ----------------
#define Bc   4
#define Tc   2048
#define Dc   1024
#define Hc   16
#define DKc  64
#define DVc  128
#define QKDc 1024
#define VDc  2048
#define Mc   (Bc * Tc)   // 8192 tokens

typedef __bf16 bf16;
typedef __bf16 bf16x4 __attribute__((ext_vector_type(4)));
typedef __bf16 bf16x8 __attribute__((ext_vector_type(8)));
typedef float  f32x4  __attribute__((ext_vector_type(4)));

__device__ __forceinline__ float bf2f(bf16 v) { return (float)v; }
__device__ __forceinline__ bf16  f2bf(float v) { return (bf16)v; }
__device__ __forceinline__ float sigmoidf_(float x) { return 1.0f / (1.0f + __expf(-x)); }

// ---------------- cast fp32 -> bf16 (vectorized) ----------------
__global__ __launch_bounds__(256) void cast_f32_bf16(const float* __restrict__ src,
                                                     bf16* __restrict__ dst, int n4) {
    int i = blockIdx.x * 256 + threadIdx.x;
    if (i < n4) {
        float4 v = ((const float4*)src)[i];
        bf16x4 o = { f2bf(v.x), f2bf(v.y), f2bf(v.z), f2bf(v.w) };
        ((bf16x4*)dst)[i] = o;
    }
}

// ---------------- transpose + cast: src fp32 [R][C] -> dst bf16 [C][R] ----------------
__global__ __launch_bounds__(256) void transpose_cast(const float* __restrict__ src,
                                                      bf16* __restrict__ dst,
                                                      int R, int C) {
    __shared__ float tile[32][33];
    int c0 = blockIdx.x * 32, r0 = blockIdx.y * 32;
    int tx = threadIdx.x, ty = threadIdx.y;  // block (32,8)
#pragma unroll
    for (int i = 0; i < 32; i += 8) {
        int r = r0 + ty + i, c = c0 + tx;
        tile[ty + i][tx] = (r < R && c < C) ? src[(size_t)r * C + c] : 0.0f;
    }
    __syncthreads();
#pragma unroll
    for (int i = 0; i < 32; i += 8) {
        int rr = c0 + ty + i, cc = r0 + tx;  // dst is [C][R]
        if (rr < C && cc < R) dst[(size_t)rr * R + cc] = f2bf(tile[tx][ty + i]);
    }
}

// ---------------- GEMM: C[M,N] = A[M,K] @ Bt[N,K]^T  (bf16 in, OutT out) ----------------
// 128x128 tile, BK=32, 256 threads (4 waves, each 64x64 quadrant via 4x4 of 16x16x32 MFMA)
// optional epilogue: C *= sigmoid(gate[row,col])
template <typename OutT>
__global__ __launch_bounds__(256) void gemm_bt(const bf16* __restrict__ A,
                                               const bf16* __restrict__ Bt,
                                               OutT* __restrict__ C,
                                               int M, int N, int K,
                                               const bf16* __restrict__ gate) {
    __shared__ bf16 As[128 * 32];
    __shared__ bf16 Bs[128 * 32];

    const int n0 = blockIdx.x * 128;
    const int m0 = blockIdx.y * 128;
    const int t = threadIdx.x;
    const int wid = t >> 6, lane = t & 63;
    const int wm = (wid & 1) * 64;
    const int wn = (wid >> 1) * 64;

    f32x4 acc[4][4] = {};

    const int r  = t >> 2;          // 0..63
    const int cq = (t & 3) * 8;     // k-chunk offset (elements)

    for (int k0 = 0; k0 < K; k0 += 32) {
        *(uint4*)&As[r * 32 + cq]        = *(const uint4*)&A[(size_t)(m0 + r) * K + k0 + cq];
        *(uint4*)&As[(r + 64) * 32 + cq] = *(const uint4*)&A[(size_t)(m0 + r + 64) * K + k0 + cq];
        *(uint4*)&Bs[r * 32 + cq]        = *(const uint4*)&Bt[(size_t)(n0 + r) * K + k0 + cq];
        *(uint4*)&Bs[(r + 64) * 32 + cq] = *(const uint4*)&Bt[(size_t)(n0 + r + 64) * K + k0 + cq];
        __syncthreads();

        const int kh = (lane >> 4) * 8;
        const int lm = lane & 15;
        bf16x8 a[4], b[4];
#pragma unroll
        for (int i = 0; i < 4; i++) a[i] = *(const bf16x8*)&As[(wm + i * 16 + lm) * 32 + kh];
#pragma unroll
        for (int j = 0; j < 4; j++) b[j] = *(const bf16x8*)&Bs[(wn + j * 16 + lm) * 32 + kh];
#pragma unroll
        for (int i = 0; i < 4; i++)
#pragma unroll
            for (int j = 0; j < 4; j++)
                acc[i][j] = __builtin_amdgcn_mfma_f32_16x16x32_bf16(a[i], b[j], acc[i][j], 0, 0, 0);
        __syncthreads();
    }

    // D[row][col]: row = (lane>>4)*4 + reg, col = lane&15  (verified layout)
    const int lm = lane & 15, lq = lane >> 4;
#pragma unroll
    for (int i = 0; i < 4; i++) {
#pragma unroll
        for (int j = 0; j < 4; j++) {
#pragma unroll
            for (int rI = 0; rI < 4; rI++) {
                int row = m0 + wm + i * 16 + lq * 4 + rI;
                int col = n0 + wn + j * 16 + lm;
                float val = acc[i][j][rI];
                if (gate) {
                    float g = bf2f(gate[(size_t)row * N + col]);
                    val *= sigmoidf_(g);
                }
                C[(size_t)row * N + col] = (OutT)val;
            }
        }
    }
}

// ---------------- zero-centered RMSNorm (in place on bf16, one block per row) ----------------
template <int L>
__global__ __launch_bounds__(256) void zc_rms_kernel(bf16* __restrict__ buf,
                                                     const float* __restrict__ scale) {
    constexpr int NPT = L / 256;
    int row = blockIdx.x;
    int t = threadIdx.x;
    bf16* p = buf + (size_t)row * L;

    float xv[NPT];
    float s = 0.f, s2 = 0.f;
#pragma unroll
    for (int i = 0; i < NPT; i++) {
        float x = bf2f(p[t + (i << 8)]);
        xv[i] = x;
        s += x;
        s2 += x * x;
    }
    __shared__ float red[2][4];
#pragma unroll
    for (int o = 32; o > 0; o >>= 1) {
        s += __shfl_down(s, o, 64);
        s2 += __shfl_down(s2, o, 64);
    }
    if ((t & 63) == 0) { red[0][t >> 6] = s; red[1][t >> 6] = s2; }
    __syncthreads();
    s  = red[0][0] + red[0][1] + red[0][2] + red[0][3];
    s2 = red[1][0] + red[1][1] + red[1][2] + red[1][3];

    float mean = s / (float)L;
    float var = s2 / (float)L - mean * mean;
    float inv = rsqrtf(var + 1e-5f);
#pragma unroll
    for (int i = 0; i < NPT; i++) {
        float y = (xv[i] - mean) * inv * scale[t + (i << 8)];
        p[t + (i << 8)] = f2bf(y);
    }
}

// ---------------- causal depthwise conv (K=4) + SiLU, bf16 in -> OutT out ----------------
template <typename OutT>
__global__ __launch_bounds__(256) void conv_silu(const bf16* __restrict__ xn,
                                                 const float* __restrict__ kern,
                                                 const float* __restrict__ bias,
                                                 OutT* __restrict__ out, int Cch) {
    int btok = blockIdx.x;          // b*T + t
    int tt = btok & (Tc - 1);       // t within sequence
    for (int c = threadIdx.x; c < Cch; c += 256) {
        float acc = bias[c];
#pragma unroll
        for (int i = 0; i < 4; i++) {
            int ts = tt - 3 + i;
            if (ts >= 0)
                acc += bf2f(xn[(size_t)(btok - 3 + i) * Cch + c]) * kern[i * Cch + c];
        }
        float y = acc * sigmoidf_(acc);
        out[(size_t)btok * Cch + c] = (OutT)y;
    }
}

// ---------------- alpha / beta: sigmoid(x @ W) for W [D,16], fp32 in ----------------
__global__ __launch_bounds__(64) void alphabeta(const float* __restrict__ x,
                                                const float* __restrict__ aw,
                                                const float* __restrict__ bw,
                                                float* __restrict__ af,
                                                float* __restrict__ bfv) {
    int tok = blockIdx.x;
    int lane = threadIdx.x;  // 1 wave
    const float* xr = x + (size_t)tok * Dc;
    float accA[16] = {};
    float accB[16] = {};
    for (int k = lane; k < Dc; k += 64) {
        float xv = xr[k];
        const float* awr = aw + (size_t)k * Hc;
        const float* bwr = bw + (size_t)k * Hc;
#pragma unroll
        for (int h = 0; h < 16; h++) {
            accA[h] += xv * awr[h];
            accB[h] += xv * bwr[h];
        }
    }
#pragma unroll
    for (int h = 0; h < 16; h++) {
        float a = accA[h], b = accB[h];
#pragma unroll
        for (int o = 32; o > 0; o >>= 1) {
            a += __shfl_down(a, o, 64);
            b += __shfl_down(b, o, 64);
        }
        if (lane == 0) {
            af[(size_t)tok * Hc + h] = sigmoidf_(a);
            bfv[(size_t)tok * Hc + h] = sigmoidf_(b);
        }
    }
}

// ---------------- gated delta-rule scan ----------------
// grid = B*H blocks, 128 threads. Thread v owns state column S[0..63][v] in registers.
__global__ __launch_bounds__(128) void scan_kernel(const float* __restrict__ qf,
                                                   const float* __restrict__ kf,
                                                   const bf16* __restrict__ vc,
                                                   const float* __restrict__ af,
                                                   const float* __restrict__ bfv,
                                                   bf16* __restrict__ o) {
    int bh = blockIdx.x;
    int b = bh >> 4, h = bh & 15;
    int v = threadIdx.x;  // 0..127

    float S[64];
#pragma unroll
    for (int d = 0; d < 64; d++) S[d] = 0.f;

    const size_t baseQK = ((size_t)b * Tc) * QKDc + (size_t)h * DKc;
    const size_t baseV  = ((size_t)b * Tc) * VDc + (size_t)h * DVc + v;
    const size_t baseAB = ((size_t)b * Tc) * Hc + h;

    for (int t = 0; t < Tc; t++) {
        const f32x4* kp = (const f32x4*)(kf + baseQK + (size_t)t * QKDc);
        const f32x4* qp = (const f32x4*)(qf + baseQK + (size_t)t * QKDc);
        float a  = af[baseAB + (size_t)t * Hc];
        float bt = bfv[baseAB + (size_t)t * Hc];
        float vv = bf2f(vc[baseV + (size_t)t * VDc]);

        float p0 = 0.f, p1 = 0.f, p2 = 0.f, p3 = 0.f;
#pragma unroll
        for (int dd = 0; dd < 16; dd++) {
            f32x4 kk = kp[dd];
            p0 += kk[0] * S[dd * 4 + 0];
            p1 += kk[1] * S[dd * 4 + 1];
            p2 += kk[2] * S[dd * 4 + 2];
            p3 += kk[3] * S[dd * 4 + 3];
        }
        float pred = (p0 + p1) + (p2 + p3);
        float delta = bt * (vv - a * pred);

        float o0 = 0.f, o1 = 0.f, o2 = 0.f, o3 = 0.f;
#pragma unroll
        for (int dd = 0; dd < 16; dd++) {
            f32x4 kk = kp[dd];
            f32x4 qq = qp[dd];
            float s0 = a * S[dd * 4 + 0] + delta * kk[0]; S[dd * 4 + 0] = s0; o0 += qq[0] * s0;
            float s1 = a * S[dd * 4 + 1] + delta * kk[1]; S[dd * 4 + 1] = s1; o1 += qq[1] * s1;
            float s2 = a * S[dd * 4 + 2] + delta * kk[2]; S[dd * 4 + 2] = s2; o2 += qq[2] * s2;
            float s3 = a * S[dd * 4 + 3] + delta * kk[3]; S[dd * 4 + 3] = s3; o3 += qq[3] * s3;
        }
        o[((size_t)(b * Tc + t)) * VDc + (size_t)h * DVc + v] = f2bf((o0 + o1) + (o2 + o3));
    }
}

// ---------------- host launch ----------------
extern "C" void kernel_launch(void* const* d_in, const int* in_sizes, int n_in,
                              void* d_out, int out_size, void* d_ws, size_t ws_size,
                              hipStream_t stream) {
    // inputs fp32 per the reference; output fp32 per the reference
    const float* x        = (const float*)d_in[0];
    const float* q_w      = (const float*)d_in[1];
    const float* k_w      = (const float*)d_in[2];
    const float* v_w      = (const float*)d_in[3];
    const float* q_scale  = (const float*)d_in[4];
    const float* k_scale  = (const float*)d_in[5];
    const float* v_scale  = (const float*)d_in[6];
    const float* q_conv_k = (const float*)d_in[7];
    const float* q_conv_b = (const float*)d_in[8];
    const float* k_conv_k = (const float*)d_in[9];
    const float* k_conv_b = (const float*)d_in[10];
    const float* v_conv_k = (const float*)d_in[11];
    const float* v_conv_b = (const float*)d_in[12];
    const float* alpha_w  = (const float*)d_in[13];
    const float* beta_w   = (const float*)d_in[14];
    const float* out_w    = (const float*)d_in[15];
    const float* gate_w   = (const float*)d_in[16];

    // ---- workspace layout (~184 MB, identical to round 2) ----
    char* w = (char*)d_ws;
    bf16* xb  = (bf16*)w; w += (size_t)Mc * Dc * 2;        // 16 MB  x cast to bf16
    bf16* qwT = (bf16*)w; w += (size_t)QKDc * Dc * 2;      //  2 MB  [QKD][D]
    bf16* kwT = (bf16*)w; w += (size_t)QKDc * Dc * 2;      //  2 MB
    bf16* vwT = (bf16*)w; w += (size_t)VDc * Dc * 2;       //  4 MB  [VD][D]
    bf16* gwT = (bf16*)w; w += (size_t)Dc * Dc * 2;        //  2 MB  [D][D]
    bf16* owT = (bf16*)w; w += (size_t)Dc * VDc * 2;       //  4 MB  [D][VD]
    bf16* q_lin = (bf16*)w; w += (size_t)Mc * QKDc * 2;    // 16 MB
    bf16* k_lin = (bf16*)w; w += (size_t)Mc * QKDc * 2;    // 16 MB
    bf16* v_lin = (bf16*)w; w += (size_t)Mc * VDc * 2;     // 32 MB
    bf16* g_lin = (bf16*)w; w += (size_t)Mc * Dc * 2;      // 16 MB
    bf16* vc  = (bf16*)w; w += (size_t)Mc * VDc * 2;       // 32 MB  conv(v) bf16
    float* kf = (float*)w; w += (size_t)Mc * QKDc * 4;     // 32 MB  conv(k) fp32
    float* af = (float*)w; w += (size_t)Mc * Hc * 4;       // 0.5 MB
    float* bfv = (float*)w; w += (size_t)Mc * Hc * 4;      // 0.5 MB
    // aliases over dead buffers:
    float* qf = (float*)v_lin;       // conv(q) fp32, 32 MB — v_lin dead after conv v
    bf16* o_core = q_lin;            // scan output, 32 MB — q_lin+k_lin dead after convs

    dim3 tb(32, 8);
    cast_f32_bf16<<<(Mc * Dc / 4 + 255) / 256, 256, 0, stream>>>(x, xb, Mc * Dc / 4);
    transpose_cast<<<dim3(QKDc / 32, Dc / 32), tb, 0, stream>>>(q_w, qwT, Dc, QKDc);
    transpose_cast<<<dim3(QKDc / 32, Dc / 32), tb, 0, stream>>>(k_w, kwT, Dc, QKDc);
    transpose_cast<<<dim3(VDc / 32, Dc / 32), tb, 0, stream>>>(v_w, vwT, Dc, VDc);
    transpose_cast<<<dim3(Dc / 32, Dc / 32), tb, 0, stream>>>(gate_w, gwT, Dc, Dc);
    transpose_cast<<<dim3(Dc / 32, VDc / 32), tb, 0, stream>>>(out_w, owT, VDc, Dc);

    // ---- V pipeline first (so v_lin dies before qf aliases it) ----
    gemm_bt<bf16><<<dim3(VDc / 128, Mc / 128), 256, 0, stream>>>(xb, vwT, v_lin, Mc, VDc, Dc, nullptr);
    zc_rms_kernel<VDc><<<Mc, 256, 0, stream>>>(v_lin, v_scale);
    conv_silu<bf16><<<Mc, 256, 0, stream>>>(v_lin, v_conv_k, v_conv_b, vc, VDc);

    // ---- Q pipeline (qf overwrites v_lin) ----
    gemm_bt<bf16><<<dim3(QKDc / 128, Mc / 128), 256, 0, stream>>>(xb, qwT, q_lin, Mc, QKDc, Dc, nullptr);
    zc_rms_kernel<QKDc><<<Mc, 256, 0, stream>>>(q_lin, q_scale);
    conv_silu<float><<<Mc, 256, 0, stream>>>(q_lin, q_conv_k, q_conv_b, qf, QKDc);

    // ---- K pipeline ----
    gemm_bt<bf16><<<dim3(QKDc / 128, Mc / 128), 256, 0, stream>>>(xb, kwT, k_lin, Mc, QKDc, Dc, nullptr);
    zc_rms_kernel<QKDc><<<Mc, 256, 0, stream>>>(k_lin, k_scale);
    conv_silu<float><<<Mc, 256, 0, stream>>>(k_lin, k_conv_k, k_conv_b, kf, QKDc);

    // ---- gate projection ----
    gemm_bt<bf16><<<dim3(Dc / 128, Mc / 128), 256, 0, stream>>>(xb, gwT, g_lin, Mc, Dc, Dc, nullptr);

    // ---- alpha/beta ----
    alphabeta<<<Mc, 64, 0, stream>>>(x, alpha_w, beta_w, af, bfv);

    // ---- sequential delta-rule scan (o_core overwrites q_lin+k_lin) ----
    scan_kernel<<<Bc * Hc, 128, 0, stream>>>(qf, kf, vc, af, bfv, o_core);

    // ---- output projection with fused sigmoid gate -> fp32 d_out ----
    gemm_bt<float><<<dim3(Dc / 128, Mc / 128), 256, 0, stream>>>(o_core, owT, (float*)d_out, Mc, Dc, VDc, g_lin);
}

// Round 4
// 1231.802 us; speedup vs baseline: 3.8459x; 3.8459x over previous
//
#include <hip/hip_runtime.h>

// ---------------- problem constants ----------------
#define Bc   4
#define Tc   2048
#define Dc   1024
#define Hc   16
#define DKc  64
#define DVc  128
#define QKDc 1024
#define VDc  2048
#define Mc   (Bc * Tc)   // 8192 tokens
#define SW   64          // scan LDS window (time steps)

typedef __bf16 bf16;
typedef __bf16 bf16x4 __attribute__((ext_vector_type(4)));
typedef __bf16 bf16x8 __attribute__((ext_vector_type(8)));
typedef float  f32x4  __attribute__((ext_vector_type(4)));

__device__ __forceinline__ float bf2f(bf16 v) { return (float)v; }
__device__ __forceinline__ bf16  f2bf(float v) { return (bf16)v; }
__device__ __forceinline__ float sigmoidf_(float x) { return 1.0f / (1.0f + __expf(-x)); }

// ---------------- cast fp32 -> bf16 (vectorized) ----------------
__global__ __launch_bounds__(256) void cast_f32_bf16(const float* __restrict__ src,
                                                     bf16* __restrict__ dst, int n4) {
    int i = blockIdx.x * 256 + threadIdx.x;
    if (i < n4) {
        float4 v = ((const float4*)src)[i];
        bf16x4 o = { f2bf(v.x), f2bf(v.y), f2bf(v.z), f2bf(v.w) };
        ((bf16x4*)dst)[i] = o;
    }
}

// ---------------- transpose + cast: src fp32 [R][C] -> dst bf16 [C][R] ----------------
__global__ __launch_bounds__(256) void transpose_cast(const float* __restrict__ src,
                                                      bf16* __restrict__ dst,
                                                      int R, int C) {
    __shared__ float tile[32][33];
    int c0 = blockIdx.x * 32, r0 = blockIdx.y * 32;
    int tx = threadIdx.x, ty = threadIdx.y;  // block (32,8)
#pragma unroll
    for (int i = 0; i < 32; i += 8) {
        int r = r0 + ty + i, c = c0 + tx;
        tile[ty + i][tx] = (r < R && c < C) ? src[(size_t)r * C + c] : 0.0f;
    }
    __syncthreads();
#pragma unroll
    for (int i = 0; i < 32; i += 8) {
        int rr = c0 + ty + i, cc = r0 + tx;  // dst is [C][R]
        if (rr < C && cc < R) dst[(size_t)rr * R + cc] = f2bf(tile[tx][ty + i]);
    }
}

// ---------------- GEMM: C[M,N] = A[M,K] @ Bt[N,K]^T  (bf16 in, OutT out) ----------------
template <typename OutT>
__global__ __launch_bounds__(256) void gemm_bt(const bf16* __restrict__ A,
                                               const bf16* __restrict__ Bt,
                                               OutT* __restrict__ C,
                                               int M, int N, int K,
                                               const bf16* __restrict__ gate) {
    __shared__ bf16 As[128 * 32];
    __shared__ bf16 Bs[128 * 32];

    const int n0 = blockIdx.x * 128;
    const int m0 = blockIdx.y * 128;
    const int t = threadIdx.x;
    const int wid = t >> 6, lane = t & 63;
    const int wm = (wid & 1) * 64;
    const int wn = (wid >> 1) * 64;

    f32x4 acc[4][4] = {};

    const int r  = t >> 2;
    const int cq = (t & 3) * 8;

    for (int k0 = 0; k0 < K; k0 += 32) {
        *(uint4*)&As[r * 32 + cq]        = *(const uint4*)&A[(size_t)(m0 + r) * K + k0 + cq];
        *(uint4*)&As[(r + 64) * 32 + cq] = *(const uint4*)&A[(size_t)(m0 + r + 64) * K + k0 + cq];
        *(uint4*)&Bs[r * 32 + cq]        = *(const uint4*)&Bt[(size_t)(n0 + r) * K + k0 + cq];
        *(uint4*)&Bs[(r + 64) * 32 + cq] = *(const uint4*)&Bt[(size_t)(n0 + r + 64) * K + k0 + cq];
        __syncthreads();

        const int kh = (lane >> 4) * 8;
        const int lm = lane & 15;
        bf16x8 a[4], b[4];
#pragma unroll
        for (int i = 0; i < 4; i++) a[i] = *(const bf16x8*)&As[(wm + i * 16 + lm) * 32 + kh];
#pragma unroll
        for (int j = 0; j < 4; j++) b[j] = *(const bf16x8*)&Bs[(wn + j * 16 + lm) * 32 + kh];
#pragma unroll
        for (int i = 0; i < 4; i++)
#pragma unroll
            for (int j = 0; j < 4; j++)
                acc[i][j] = __builtin_amdgcn_mfma_f32_16x16x32_bf16(a[i], b[j], acc[i][j], 0, 0, 0);
        __syncthreads();
    }

    const int lm = lane & 15, lq = lane >> 4;
#pragma unroll
    for (int i = 0; i < 4; i++) {
#pragma unroll
        for (int j = 0; j < 4; j++) {
#pragma unroll
            for (int rI = 0; rI < 4; rI++) {
                int row = m0 + wm + i * 16 + lq * 4 + rI;
                int col = n0 + wn + j * 16 + lm;
                float val = acc[i][j][rI];
                if (gate) {
                    float g = bf2f(gate[(size_t)row * N + col]);
                    val *= sigmoidf_(g);
                }
                C[(size_t)row * N + col] = (OutT)val;
            }
        }
    }
}

// ---------------- zero-centered RMSNorm (in place on bf16, one block per row) ----------------
template <int L>
__global__ __launch_bounds__(256) void zc_rms_kernel(bf16* __restrict__ buf,
                                                     const float* __restrict__ scale) {
    constexpr int NPT = L / 256;
    int row = blockIdx.x;
    int t = threadIdx.x;
    bf16* p = buf + (size_t)row * L;

    float xv[NPT];
    float s = 0.f, s2 = 0.f;
#pragma unroll
    for (int i = 0; i < NPT; i++) {
        float x = bf2f(p[t + (i << 8)]);
        xv[i] = x;
        s += x;
        s2 += x * x;
    }
    __shared__ float red[2][4];
#pragma unroll
    for (int o = 32; o > 0; o >>= 1) {
        s += __shfl_down(s, o, 64);
        s2 += __shfl_down(s2, o, 64);
    }
    if ((t & 63) == 0) { red[0][t >> 6] = s; red[1][t >> 6] = s2; }
    __syncthreads();
    s  = red[0][0] + red[0][1] + red[0][2] + red[0][3];
    s2 = red[1][0] + red[1][1] + red[1][2] + red[1][3];

    float mean = s / (float)L;
    float var = s2 / (float)L - mean * mean;
    float inv = rsqrtf(var + 1e-5f);
#pragma unroll
    for (int i = 0; i < NPT; i++) {
        float y = (xv[i] - mean) * inv * scale[t + (i << 8)];
        p[t + (i << 8)] = f2bf(y);
    }
}

// ---------------- causal depthwise conv (K=4) + SiLU, bf16 in -> OutT out ----------------
template <typename OutT>
__global__ __launch_bounds__(256) void conv_silu(const bf16* __restrict__ xn,
                                                 const float* __restrict__ kern,
                                                 const float* __restrict__ bias,
                                                 OutT* __restrict__ out, int Cch) {
    int btok = blockIdx.x;
    int tt = btok & (Tc - 1);
    for (int c = threadIdx.x; c < Cch; c += 256) {
        float acc = bias[c];
#pragma unroll
        for (int i = 0; i < 4; i++) {
            int ts = tt - 3 + i;
            if (ts >= 0)
                acc += bf2f(xn[(size_t)(btok - 3 + i) * Cch + c]) * kern[i * Cch + c];
        }
        float y = acc * sigmoidf_(acc);
        out[(size_t)btok * Cch + c] = (OutT)y;
    }
}

// ---------------- alpha / beta: sigmoid(x @ W) for W [D,16], fp32 in ----------------
__global__ __launch_bounds__(64) void alphabeta(const float* __restrict__ x,
                                                const float* __restrict__ aw,
                                                const float* __restrict__ bw,
                                                float* __restrict__ af,
                                                float* __restrict__ bfv) {
    int tok = blockIdx.x;
    int lane = threadIdx.x;
    const float* xr = x + (size_t)tok * Dc;
    float accA[16] = {};
    float accB[16] = {};
    for (int k = lane; k < Dc; k += 64) {
        float xv = xr[k];
        const float* awr = aw + (size_t)k * Hc;
        const float* bwr = bw + (size_t)k * Hc;
#pragma unroll
        for (int h = 0; h < 16; h++) {
            accA[h] += xv * awr[h];
            accB[h] += xv * bwr[h];
        }
    }
#pragma unroll
    for (int h = 0; h < 16; h++) {
        float a = accA[h], b = accB[h];
#pragma unroll
        for (int o = 32; o > 0; o >>= 1) {
            a += __shfl_down(a, o, 64);
            b += __shfl_down(b, o, 64);
        }
        if (lane == 0) {
            af[(size_t)tok * Hc + h] = sigmoidf_(a);
            bfv[(size_t)tok * Hc + h] = sigmoidf_(b);
        }
    }
}

// ---------------- gated delta-rule scan, v2 ----------------
// grid = (4 vgroups, 64 bh), 256 threads. lane: dgrp = lane&7 (owns d = dgrp*8+j),
// column = wave*8 + lane>>3 (8 cols/wave, 32 cols/block). pred & o via xor-butterfly
// over dgrp bits. K/Q/V/a/b staged in LDS 64-step windows, double-buffered.
__global__ __launch_bounds__(256) void scan2(const float* __restrict__ qf,
                                             const float* __restrict__ kf,
                                             const bf16* __restrict__ vc,
                                             const float* __restrict__ af,
                                             const float* __restrict__ bfv,
                                             bf16* __restrict__ o) {
    const int vg = blockIdx.x;                 // 0..3
    const int bh = blockIdx.y;                 // 0..63
    const int b = bh >> 4, h = bh & 15;
    const int tid = threadIdx.x;
    const int wave = tid >> 6, lane = tid & 63;
    const int dgrp = lane & 7;                 // d-range dgrp*8..+7
    const int vloc = wave * 8 + (lane >> 3);   // 0..31 column within block

    __shared__ float k_lds[2][SW][64];
    __shared__ float q_lds[2][SW][64];
    __shared__ float v_lds[2][SW][32];
    __shared__ float a_lds[2][SW];
    __shared__ float b_lds[2][SW];
    __shared__ bf16  o_tile[SW][32];

    const size_t base_kq = ((size_t)b * Tc) * QKDc + (size_t)h * DKc;
    const size_t base_v  = ((size_t)b * Tc) * VDc + (size_t)h * DVc + (size_t)vg * 32;
    const size_t base_ab = ((size_t)b * Tc) * Hc + h;

    float S[8];
#pragma unroll
    for (int j = 0; j < 8; j++) S[j] = 0.f;

    // staging registers
    f32x4 kr[4], qr[4];
    bf16x8 vr;
    float abr = 0.f;

    // stage-load window starting at t0 into registers
    auto stage_load = [&](int t0) {
#pragma unroll
        for (int i = 0; i < 4; i++) {
            int c = tid + i * 256;             // float4 chunk id, 16 chunks/row
            int row = c >> 4, colb = (c & 15) * 4;
            kr[i] = *(const f32x4*)&kf[base_kq + (size_t)(t0 + row) * QKDc + colb];
            qr[i] = *(const f32x4*)&qf[base_kq + (size_t)(t0 + row) * QKDc + colb];
        }
        {
            int row = tid >> 2, colb = (tid & 3) * 8;
            vr = *(const bf16x8*)&vc[base_v + (size_t)(t0 + row) * VDc + colb];
        }
        if (tid < SW) abr = af[base_ab + (size_t)(t0 + tid) * Hc];
        else if (tid < 2 * SW) abr = bfv[base_ab + (size_t)(t0 + tid - SW) * Hc];
    };

    auto stage_write = [&](int buf) {
#pragma unroll
        for (int i = 0; i < 4; i++) {
            int c = tid + i * 256;
            int row = c >> 4, colb = (c & 15) * 4;
            *(f32x4*)&k_lds[buf][row][colb] = kr[i];
            *(f32x4*)&q_lds[buf][row][colb] = qr[i];
        }
        {
            int row = tid >> 2, colb = (tid & 3) * 8;
            f32x4 lo = { bf2f(vr[0]), bf2f(vr[1]), bf2f(vr[2]), bf2f(vr[3]) };
            f32x4 hi = { bf2f(vr[4]), bf2f(vr[5]), bf2f(vr[6]), bf2f(vr[7]) };
            *(f32x4*)&v_lds[buf][row][colb]     = lo;
            *(f32x4*)&v_lds[buf][row][colb + 4] = hi;
        }
        if (tid < SW) a_lds[buf][tid] = abr;
        else if (tid < 2 * SW) b_lds[buf][tid - SW] = abr;
    };

    stage_load(0);
    stage_write(0);
    __syncthreads();

    const int nwin = Tc / SW;   // 32
    for (int w = 0; w < nwin; w++) {
        const int buf = w & 1;
        if (w + 1 < nwin) stage_load((w + 1) * SW);   // overlap HBM with compute

#pragma unroll 4
        for (int t = 0; t < SW; t++) {
            f32x4 k0 = *(const f32x4*)&k_lds[buf][t][dgrp * 8];
            f32x4 k1 = *(const f32x4*)&k_lds[buf][t][dgrp * 8 + 4];
            f32x4 q0 = *(const f32x4*)&q_lds[buf][t][dgrp * 8];
            f32x4 q1 = *(const f32x4*)&q_lds[buf][t][dgrp * 8 + 4];
            float a  = a_lds[buf][t];
            float bb = b_lds[buf][t];
            float vv = v_lds[buf][t][vloc];

            float pA = k0[0] * S[0] + k0[2] * S[2];
            float pB = k0[1] * S[1] + k0[3] * S[3];
            pA += k1[0] * S[4] + k1[2] * S[6];
            pB += k1[1] * S[5] + k1[3] * S[7];
            float p = pA + pB;
            p += __shfl_xor(p, 1, 64);
            p += __shfl_xor(p, 2, 64);
            p += __shfl_xor(p, 4, 64);

            float delta = bb * (vv - a * p);

            float oA = 0.f, oB = 0.f;
#pragma unroll
            for (int j = 0; j < 4; j++) {
                float s0 = a * S[j] + delta * k0[j];
                S[j] = s0;
                if (j & 1) oB += q0[j] * s0; else oA += q0[j] * s0;
                float s1 = a * S[4 + j] + delta * k1[j];
                S[4 + j] = s1;
                if (j & 1) oB += q1[j] * s1; else oA += q1[j] * s1;
            }
            float oo = oA + oB;
            oo += __shfl_xor(oo, 1, 64);
            oo += __shfl_xor(oo, 2, 64);
            oo += __shfl_xor(oo, 4, 64);
            if (dgrp == 0) o_tile[t][vloc] = f2bf(oo);
        }
        __syncthreads();   // o_tile complete; current buf free for rewrite

        // flush o_tile (coalesced, 8 bf16 per thread)
        {
            int row = tid >> 2, colb = (tid & 3) * 8;
            *(uint4*)&o[base_v + (size_t)(w * SW + row) * VDc + colb] =
                *(const uint4*)&o_tile[row][colb];
        }
        if (w + 1 < nwin) stage_write((w + 1) & 1);
        __syncthreads();
    }
}

// ---------------- host launch ----------------
extern "C" void kernel_launch(void* const* d_in, const int* in_sizes, int n_in,
                              void* d_out, int out_size, void* d_ws, size_t ws_size,
                              hipStream_t stream) {
    const float* x        = (const float*)d_in[0];
    const float* q_w      = (const float*)d_in[1];
    const float* k_w      = (const float*)d_in[2];
    const float* v_w      = (const float*)d_in[3];
    const float* q_scale  = (const float*)d_in[4];
    const float* k_scale  = (const float*)d_in[5];
    const float* v_scale  = (const float*)d_in[6];
    const float* q_conv_k = (const float*)d_in[7];
    const float* q_conv_b = (const float*)d_in[8];
    const float* k_conv_k = (const float*)d_in[9];
    const float* k_conv_b = (const float*)d_in[10];
    const float* v_conv_k = (const float*)d_in[11];
    const float* v_conv_b = (const float*)d_in[12];
    const float* alpha_w  = (const float*)d_in[13];
    const float* beta_w   = (const float*)d_in[14];
    const float* out_w    = (const float*)d_in[15];
    const float* gate_w   = (const float*)d_in[16];

    char* w = (char*)d_ws;
    bf16* xb  = (bf16*)w; w += (size_t)Mc * Dc * 2;
    bf16* qwT = (bf16*)w; w += (size_t)QKDc * Dc * 2;
    bf16* kwT = (bf16*)w; w += (size_t)QKDc * Dc * 2;
    bf16* vwT = (bf16*)w; w += (size_t)VDc * Dc * 2;
    bf16* gwT = (bf16*)w; w += (size_t)Dc * Dc * 2;
    bf16* owT = (bf16*)w; w += (size_t)Dc * VDc * 2;
    bf16* q_lin = (bf16*)w; w += (size_t)Mc * QKDc * 2;
    bf16* k_lin = (bf16*)w; w += (size_t)Mc * QKDc * 2;
    bf16* v_lin = (bf16*)w; w += (size_t)Mc * VDc * 2;
    bf16* g_lin = (bf16*)w; w += (size_t)Mc * Dc * 2;
    bf16* vc  = (bf16*)w; w += (size_t)Mc * VDc * 2;
    float* kf = (float*)w; w += (size_t)Mc * QKDc * 4;
    float* af = (float*)w; w += (size_t)Mc * Hc * 4;
    float* bfv = (float*)w; w += (size_t)Mc * Hc * 4;
    float* qf = (float*)v_lin;       // alias: v_lin dead after conv v
    bf16* o_core = q_lin;            // alias: q_lin+k_lin dead after convs

    dim3 tb(32, 8);
    cast_f32_bf16<<<(Mc * Dc / 4 + 255) / 256, 256, 0, stream>>>(x, xb, Mc * Dc / 4);
    transpose_cast<<<dim3(QKDc / 32, Dc / 32), tb, 0, stream>>>(q_w, qwT, Dc, QKDc);
    transpose_cast<<<dim3(QKDc / 32, Dc / 32), tb, 0, stream>>>(k_w, kwT, Dc, QKDc);
    transpose_cast<<<dim3(VDc / 32, Dc / 32), tb, 0, stream>>>(v_w, vwT, Dc, VDc);
    transpose_cast<<<dim3(Dc / 32, Dc / 32), tb, 0, stream>>>(gate_w, gwT, Dc, Dc);
    transpose_cast<<<dim3(Dc / 32, VDc / 32), tb, 0, stream>>>(out_w, owT, VDc, Dc);

    // V pipeline first (v_lin dies before qf aliases it)
    gemm_bt<bf16><<<dim3(VDc / 128, Mc / 128), 256, 0, stream>>>(xb, vwT, v_lin, Mc, VDc, Dc, nullptr);
    zc_rms_kernel<VDc><<<Mc, 256, 0, stream>>>(v_lin, v_scale);
    conv_silu<bf16><<<Mc, 256, 0, stream>>>(v_lin, v_conv_k, v_conv_b, vc, VDc);

    // Q pipeline (qf overwrites v_lin)
    gemm_bt<bf16><<<dim3(QKDc / 128, Mc / 128), 256, 0, stream>>>(xb, qwT, q_lin, Mc, QKDc, Dc, nullptr);
    zc_rms_kernel<QKDc><<<Mc, 256, 0, stream>>>(q_lin, q_scale);
    conv_silu<float><<<Mc, 256, 0, stream>>>(q_lin, q_conv_k, q_conv_b, qf, QKDc);

    // K pipeline
    gemm_bt<bf16><<<dim3(QKDc / 128, Mc / 128), 256, 0, stream>>>(xb, kwT, k_lin, Mc, QKDc, Dc, nullptr);
    zc_rms_kernel<QKDc><<<Mc, 256, 0, stream>>>(k_lin, k_scale);
    conv_silu<float><<<Mc, 256, 0, stream>>>(k_lin, k_conv_k, k_conv_b, kf, QKDc);

    // gate projection
    gemm_bt<bf16><<<dim3(Dc / 128, Mc / 128), 256, 0, stream>>>(xb, gwT, g_lin, Mc, Dc, Dc, nullptr);

    // alpha/beta
    alphabeta<<<Mc, 64, 0, stream>>>(x, alpha_w, beta_w, af, bfv);

    // parallel-restructured delta-rule scan
    scan2<<<dim3(4, Bc * Hc), 256, 0, stream>>>(qf, kf, vc, af, bfv, o_core);

    // output projection with fused sigmoid gate -> fp32 d_out
    gemm_bt<float><<<dim3(Dc / 128, Mc / 128), 256, 0, stream>>>(o_core, owT, (float*)d_out, Mc, Dc, VDc, g_lin);
}

// Round 5
// 936.964 us; speedup vs baseline: 5.0561x; 1.3147x over previous
//
#include <hip/hip_runtime.h>

// ---------------- problem constants ----------------
#define Bc   4
#define Tc   2048
#define Dc   1024
#define Hc   16
#define DKc  64
#define DVc  128
#define QKDc 1024
#define VDc  2048
#define Mc   (Bc * Tc)   // 8192 tokens
#define SW   64          // scan LDS window (time steps)

typedef __bf16 bf16;
typedef __bf16 bf16x4 __attribute__((ext_vector_type(4)));
typedef __bf16 bf16x8 __attribute__((ext_vector_type(8)));
typedef float  f32x4  __attribute__((ext_vector_type(4)));

__device__ __forceinline__ float bf2f(bf16 v) { return (float)v; }
__device__ __forceinline__ bf16  f2bf(float v) { return (bf16)v; }
__device__ __forceinline__ float sigmoidf_(float x) { return 1.0f / (1.0f + __expf(-x)); }

// DPP-based add: x + lane_perm(x). Runs in VALU pipe (~4 cyc), not LDS pipe.
// ctrl: 0xB1 = quad_perm [1,0,3,2] (xor-1), 0x4E = quad_perm [2,3,0,1] (xor-2),
//       0x141 = ROW_HALF_MIRROR (combines the two quads of each 8-lane group).
template <int CTRL>
__device__ __forceinline__ float dpp_add(float x) {
    int xi = __float_as_int(x);
    int yi = __builtin_amdgcn_update_dpp(0, xi, CTRL, 0xF, 0xF, true);
    return x + __int_as_float(yi);
}
// full sum over each aligned 8-lane group
__device__ __forceinline__ float reduce8(float x) {
    x = dpp_add<0xB1>(x);
    x = dpp_add<0x4E>(x);
    x = dpp_add<0x141>(x);
    return x;
}

// ---------------- cast fp32 -> bf16 (vectorized) ----------------
__global__ __launch_bounds__(256) void cast_f32_bf16(const float* __restrict__ src,
                                                     bf16* __restrict__ dst, int n4) {
    int i = blockIdx.x * 256 + threadIdx.x;
    if (i < n4) {
        float4 v = ((const float4*)src)[i];
        bf16x4 o = { f2bf(v.x), f2bf(v.y), f2bf(v.z), f2bf(v.w) };
        ((bf16x4*)dst)[i] = o;
    }
}

// ---------------- transpose + cast: src fp32 [R][C] -> dst bf16 [C][R] ----------------
__global__ __launch_bounds__(256) void transpose_cast(const float* __restrict__ src,
                                                      bf16* __restrict__ dst,
                                                      int R, int C) {
    __shared__ float tile[32][33];
    int c0 = blockIdx.x * 32, r0 = blockIdx.y * 32;
    int tx = threadIdx.x, ty = threadIdx.y;  // block (32,8)
#pragma unroll
    for (int i = 0; i < 32; i += 8) {
        int r = r0 + ty + i, c = c0 + tx;
        tile[ty + i][tx] = (r < R && c < C) ? src[(size_t)r * C + c] : 0.0f;
    }
    __syncthreads();
#pragma unroll
    for (int i = 0; i < 32; i += 8) {
        int rr = c0 + ty + i, cc = r0 + tx;  // dst is [C][R]
        if (rr < C && cc < R) dst[(size_t)rr * R + cc] = f2bf(tile[tx][ty + i]);
    }
}

// ---------------- GEMM: C[M,N] = A[M,K] @ Bt[N,K]^T  (bf16 in, OutT out) ----------------
template <typename OutT>
__global__ __launch_bounds__(256) void gemm_bt(const bf16* __restrict__ A,
                                               const bf16* __restrict__ Bt,
                                               OutT* __restrict__ C,
                                               int M, int N, int K,
                                               const bf16* __restrict__ gate) {
    __shared__ bf16 As[128 * 32];
    __shared__ bf16 Bs[128 * 32];

    const int n0 = blockIdx.x * 128;
    const int m0 = blockIdx.y * 128;
    const int t = threadIdx.x;
    const int wid = t >> 6, lane = t & 63;
    const int wm = (wid & 1) * 64;
    const int wn = (wid >> 1) * 64;

    f32x4 acc[4][4] = {};

    const int r  = t >> 2;
    const int cq = (t & 3) * 8;

    for (int k0 = 0; k0 < K; k0 += 32) {
        *(uint4*)&As[r * 32 + cq]        = *(const uint4*)&A[(size_t)(m0 + r) * K + k0 + cq];
        *(uint4*)&As[(r + 64) * 32 + cq] = *(const uint4*)&A[(size_t)(m0 + r + 64) * K + k0 + cq];
        *(uint4*)&Bs[r * 32 + cq]        = *(const uint4*)&Bt[(size_t)(n0 + r) * K + k0 + cq];
        *(uint4*)&Bs[(r + 64) * 32 + cq] = *(const uint4*)&Bt[(size_t)(n0 + r + 64) * K + k0 + cq];
        __syncthreads();

        const int kh = (lane >> 4) * 8;
        const int lm = lane & 15;
        bf16x8 a[4], b[4];
#pragma unroll
        for (int i = 0; i < 4; i++) a[i] = *(const bf16x8*)&As[(wm + i * 16 + lm) * 32 + kh];
#pragma unroll
        for (int j = 0; j < 4; j++) b[j] = *(const bf16x8*)&Bs[(wn + j * 16 + lm) * 32 + kh];
#pragma unroll
        for (int i = 0; i < 4; i++)
#pragma unroll
            for (int j = 0; j < 4; j++)
                acc[i][j] = __builtin_amdgcn_mfma_f32_16x16x32_bf16(a[i], b[j], acc[i][j], 0, 0, 0);
        __syncthreads();
    }

    const int lm = lane & 15, lq = lane >> 4;
#pragma unroll
    for (int i = 0; i < 4; i++) {
#pragma unroll
        for (int j = 0; j < 4; j++) {
#pragma unroll
            for (int rI = 0; rI < 4; rI++) {
                int row = m0 + wm + i * 16 + lq * 4 + rI;
                int col = n0 + wn + j * 16 + lm;
                float val = acc[i][j][rI];
                if (gate) {
                    float g = bf2f(gate[(size_t)row * N + col]);
                    val *= sigmoidf_(g);
                }
                C[(size_t)row * N + col] = (OutT)val;
            }
        }
    }
}

// ---------------- zero-centered RMSNorm (in place on bf16, one block per row) ----------------
template <int L>
__global__ __launch_bounds__(256) void zc_rms_kernel(bf16* __restrict__ buf,
                                                     const float* __restrict__ scale) {
    constexpr int NPT = L / 256;
    int row = blockIdx.x;
    int t = threadIdx.x;
    bf16* p = buf + (size_t)row * L;

    float xv[NPT];
    float s = 0.f, s2 = 0.f;
#pragma unroll
    for (int i = 0; i < NPT; i++) {
        float x = bf2f(p[t + (i << 8)]);
        xv[i] = x;
        s += x;
        s2 += x * x;
    }
    __shared__ float red[2][4];
#pragma unroll
    for (int o = 32; o > 0; o >>= 1) {
        s += __shfl_down(s, o, 64);
        s2 += __shfl_down(s2, o, 64);
    }
    if ((t & 63) == 0) { red[0][t >> 6] = s; red[1][t >> 6] = s2; }
    __syncthreads();
    s  = red[0][0] + red[0][1] + red[0][2] + red[0][3];
    s2 = red[1][0] + red[1][1] + red[1][2] + red[1][3];

    float mean = s / (float)L;
    float var = s2 / (float)L - mean * mean;
    float inv = rsqrtf(var + 1e-5f);
#pragma unroll
    for (int i = 0; i < NPT; i++) {
        float y = (xv[i] - mean) * inv * scale[t + (i << 8)];
        p[t + (i << 8)] = f2bf(y);
    }
}

// ---------------- causal depthwise conv (K=4) + SiLU, bf16 in -> OutT out ----------------
template <typename OutT>
__global__ __launch_bounds__(256) void conv_silu(const bf16* __restrict__ xn,
                                                 const float* __restrict__ kern,
                                                 const float* __restrict__ bias,
                                                 OutT* __restrict__ out, int Cch) {
    int btok = blockIdx.x;
    int tt = btok & (Tc - 1);
    for (int c = threadIdx.x; c < Cch; c += 256) {
        float acc = bias[c];
#pragma unroll
        for (int i = 0; i < 4; i++) {
            int ts = tt - 3 + i;
            if (ts >= 0)
                acc += bf2f(xn[(size_t)(btok - 3 + i) * Cch + c]) * kern[i * Cch + c];
        }
        float y = acc * sigmoidf_(acc);
        out[(size_t)btok * Cch + c] = (OutT)y;
    }
}

// ---------------- alpha / beta: sigmoid(x @ W) for W [D,16], fp32 in ----------------
__global__ __launch_bounds__(64) void alphabeta(const float* __restrict__ x,
                                                const float* __restrict__ aw,
                                                const float* __restrict__ bw,
                                                float* __restrict__ af,
                                                float* __restrict__ bfv) {
    int tok = blockIdx.x;
    int lane = threadIdx.x;
    const float* xr = x + (size_t)tok * Dc;
    float accA[16] = {};
    float accB[16] = {};
    for (int k = lane; k < Dc; k += 64) {
        float xv = xr[k];
        const float* awr = aw + (size_t)k * Hc;
        const float* bwr = bw + (size_t)k * Hc;
#pragma unroll
        for (int h = 0; h < 16; h++) {
            accA[h] += xv * awr[h];
            accB[h] += xv * bwr[h];
        }
    }
#pragma unroll
    for (int h = 0; h < 16; h++) {
        float a = accA[h], b = accB[h];
#pragma unroll
        for (int o = 32; o > 0; o >>= 1) {
            a += __shfl_down(a, o, 64);
            b += __shfl_down(b, o, 64);
        }
        if (lane == 0) {
            af[(size_t)tok * Hc + h] = sigmoidf_(a);
            bfv[(size_t)tok * Hc + h] = sigmoidf_(b);
        }
    }
}

// ---------------- gated delta-rule scan, v3: DPP reductions ----------------
// grid = (4 vgroups, 64 bh), 256 threads. dgrp = lane&7 owns d = dgrp*8..+7,
// column = wave*8 + lane>>3. Reductions over the 8-lane dgrp groups use DPP
// (VALU pipe, ~4 cyc) instead of ds_permute shuffles (~110 cyc) — the round-4
// critical path was 6 serial LDS-pipe shuffles = ~660 of 785 cyc/step.
__global__ __launch_bounds__(256) void scan3(const float* __restrict__ qf,
                                             const float* __restrict__ kf,
                                             const bf16* __restrict__ vc,
                                             const float* __restrict__ af,
                                             const float* __restrict__ bfv,
                                             bf16* __restrict__ o) {
    const int vg = blockIdx.x;                 // 0..3
    const int bh = blockIdx.y;                 // 0..63
    const int b = bh >> 4, h = bh & 15;
    const int tid = threadIdx.x;
    const int wave = tid >> 6, lane = tid & 63;
    const int dgrp = lane & 7;                 // d-range dgrp*8..+7
    const int vloc = wave * 8 + (lane >> 3);   // 0..31 column within block

    __shared__ float k_lds[2][SW][64];
    __shared__ float q_lds[2][SW][64];
    __shared__ float v_lds[2][SW][32];
    __shared__ float a_lds[2][SW];
    __shared__ float b_lds[2][SW];
    __shared__ bf16  o_tile[SW][32];

    const size_t base_kq = ((size_t)b * Tc) * QKDc + (size_t)h * DKc;
    const size_t base_v  = ((size_t)b * Tc) * VDc + (size_t)h * DVc + (size_t)vg * 32;
    const size_t base_ab = ((size_t)b * Tc) * Hc + h;

    float S[8];
#pragma unroll
    for (int j = 0; j < 8; j++) S[j] = 0.f;

    f32x4 kr[4], qr[4];
    bf16x8 vr;
    float abr = 0.f;

    auto stage_load = [&](int t0) {
#pragma unroll
        for (int i = 0; i < 4; i++) {
            int c = tid + i * 256;             // float4 chunk id, 16 chunks/row
            int row = c >> 4, colb = (c & 15) * 4;
            kr[i] = *(const f32x4*)&kf[base_kq + (size_t)(t0 + row) * QKDc + colb];
            qr[i] = *(const f32x4*)&qf[base_kq + (size_t)(t0 + row) * QKDc + colb];
        }
        {
            int row = tid >> 2, colb = (tid & 3) * 8;
            vr = *(const bf16x8*)&vc[base_v + (size_t)(t0 + row) * VDc + colb];
        }
        if (tid < SW) abr = af[base_ab + (size_t)(t0 + tid) * Hc];
        else if (tid < 2 * SW) abr = bfv[base_ab + (size_t)(t0 + tid - SW) * Hc];
    };

    auto stage_write = [&](int buf) {
#pragma unroll
        for (int i = 0; i < 4; i++) {
            int c = tid + i * 256;
            int row = c >> 4, colb = (c & 15) * 4;
            *(f32x4*)&k_lds[buf][row][colb] = kr[i];
            *(f32x4*)&q_lds[buf][row][colb] = qr[i];
        }
        {
            int row = tid >> 2, colb = (tid & 3) * 8;
            f32x4 lo = { bf2f(vr[0]), bf2f(vr[1]), bf2f(vr[2]), bf2f(vr[3]) };
            f32x4 hi = { bf2f(vr[4]), bf2f(vr[5]), bf2f(vr[6]), bf2f(vr[7]) };
            *(f32x4*)&v_lds[buf][row][colb]     = lo;
            *(f32x4*)&v_lds[buf][row][colb + 4] = hi;
        }
        if (tid < SW) a_lds[buf][tid] = abr;
        else if (tid < 2 * SW) b_lds[buf][tid - SW] = abr;
    };

    stage_load(0);
    stage_write(0);
    __syncthreads();

    const int nwin = Tc / SW;   // 32
    for (int w = 0; w < nwin; w++) {
        const int buf = w & 1;
        if (w + 1 < nwin) stage_load((w + 1) * SW);   // overlap HBM with compute

#pragma unroll 4
        for (int t = 0; t < SW; t++) {
            f32x4 k0 = *(const f32x4*)&k_lds[buf][t][dgrp * 8];
            f32x4 k1 = *(const f32x4*)&k_lds[buf][t][dgrp * 8 + 4];
            f32x4 q0 = *(const f32x4*)&q_lds[buf][t][dgrp * 8];
            f32x4 q1 = *(const f32x4*)&q_lds[buf][t][dgrp * 8 + 4];
            float a  = a_lds[buf][t];
            float bb = b_lds[buf][t];
            float vv = v_lds[buf][t][vloc];

            float pA = k0[0] * S[0] + k0[2] * S[2];
            float pB = k0[1] * S[1] + k0[3] * S[3];
            pA += k1[0] * S[4] + k1[2] * S[6];
            pB += k1[1] * S[5] + k1[3] * S[7];
            float p = reduce8(pA + pB);        // DPP: VALU-pipe 8-lane sum

            float delta = bb * (vv - a * p);

            float oA = 0.f, oB = 0.f;
#pragma unroll
            for (int j = 0; j < 4; j++) {
                float s0 = a * S[j] + delta * k0[j];
                S[j] = s0;
                if (j & 1) oB += q0[j] * s0; else oA += q0[j] * s0;
                float s1 = a * S[4 + j] + delta * k1[j];
                S[4 + j] = s1;
                if (j & 1) oB += q1[j] * s1; else oA += q1[j] * s1;
            }
            float oo = reduce8(oA + oB);       // off the recurrence chain
            if (dgrp == 0) o_tile[t][vloc] = f2bf(oo);
        }
        __syncthreads();   // o_tile complete; current buf free for rewrite

        {
            int row = tid >> 2, colb = (tid & 3) * 8;
            *(uint4*)&o[base_v + (size_t)(w * SW + row) * VDc + colb] =
                *(const uint4*)&o_tile[row][colb];
        }
        if (w + 1 < nwin) stage_write((w + 1) & 1);
        __syncthreads();
    }
}

// ---------------- host launch ----------------
extern "C" void kernel_launch(void* const* d_in, const int* in_sizes, int n_in,
                              void* d_out, int out_size, void* d_ws, size_t ws_size,
                              hipStream_t stream) {
    const float* x        = (const float*)d_in[0];
    const float* q_w      = (const float*)d_in[1];
    const float* k_w      = (const float*)d_in[2];
    const float* v_w      = (const float*)d_in[3];
    const float* q_scale  = (const float*)d_in[4];
    const float* k_scale  = (const float*)d_in[5];
    const float* v_scale  = (const float*)d_in[6];
    const float* q_conv_k = (const float*)d_in[7];
    const float* q_conv_b = (const float*)d_in[8];
    const float* k_conv_k = (const float*)d_in[9];
    const float* k_conv_b = (const float*)d_in[10];
    const float* v_conv_k = (const float*)d_in[11];
    const float* v_conv_b = (const float*)d_in[12];
    const float* alpha_w  = (const float*)d_in[13];
    const float* beta_w   = (const float*)d_in[14];
    const float* out_w    = (const float*)d_in[15];
    const float* gate_w   = (const float*)d_in[16];

    char* w = (char*)d_ws;
    bf16* xb  = (bf16*)w; w += (size_t)Mc * Dc * 2;
    bf16* qwT = (bf16*)w; w += (size_t)QKDc * Dc * 2;
    bf16* kwT = (bf16*)w; w += (size_t)QKDc * Dc * 2;
    bf16* vwT = (bf16*)w; w += (size_t)VDc * Dc * 2;
    bf16* gwT = (bf16*)w; w += (size_t)Dc * Dc * 2;
    bf16* owT = (bf16*)w; w += (size_t)Dc * VDc * 2;
    bf16* q_lin = (bf16*)w; w += (size_t)Mc * QKDc * 2;
    bf16* k_lin = (bf16*)w; w += (size_t)Mc * QKDc * 2;
    bf16* v_lin = (bf16*)w; w += (size_t)Mc * VDc * 2;
    bf16* g_lin = (bf16*)w; w += (size_t)Mc * Dc * 2;
    bf16* vc  = (bf16*)w; w += (size_t)Mc * VDc * 2;
    float* kf = (float*)w; w += (size_t)Mc * QKDc * 4;
    float* af = (float*)w; w += (size_t)Mc * Hc * 4;
    float* bfv = (float*)w; w += (size_t)Mc * Hc * 4;
    float* qf = (float*)v_lin;       // alias: v_lin dead after conv v
    bf16* o_core = q_lin;            // alias: q_lin+k_lin dead after convs

    dim3 tb(32, 8);
    cast_f32_bf16<<<(Mc * Dc / 4 + 255) / 256, 256, 0, stream>>>(x, xb, Mc * Dc / 4);
    transpose_cast<<<dim3(QKDc / 32, Dc / 32), tb, 0, stream>>>(q_w, qwT, Dc, QKDc);
    transpose_cast<<<dim3(QKDc / 32, Dc / 32), tb, 0, stream>>>(k_w, kwT, Dc, QKDc);
    transpose_cast<<<dim3(VDc / 32, Dc / 32), tb, 0, stream>>>(v_w, vwT, Dc, VDc);
    transpose_cast<<<dim3(Dc / 32, Dc / 32), tb, 0, stream>>>(gate_w, gwT, Dc, Dc);
    transpose_cast<<<dim3(Dc / 32, VDc / 32), tb, 0, stream>>>(out_w, owT, VDc, Dc);

    // V pipeline first (v_lin dies before qf aliases it)
    gemm_bt<bf16><<<dim3(VDc / 128, Mc / 128), 256, 0, stream>>>(xb, vwT, v_lin, Mc, VDc, Dc, nullptr);
    zc_rms_kernel<VDc><<<Mc, 256, 0, stream>>>(v_lin, v_scale);
    conv_silu<bf16><<<Mc, 256, 0, stream>>>(v_lin, v_conv_k, v_conv_b, vc, VDc);

    // Q pipeline (qf overwrites v_lin)
    gemm_bt<bf16><<<dim3(QKDc / 128, Mc / 128), 256, 0, stream>>>(xb, qwT, q_lin, Mc, QKDc, Dc, nullptr);
    zc_rms_kernel<QKDc><<<Mc, 256, 0, stream>>>(q_lin, q_scale);
    conv_silu<float><<<Mc, 256, 0, stream>>>(q_lin, q_conv_k, q_conv_b, qf, QKDc);

    // K pipeline
    gemm_bt<bf16><<<dim3(QKDc / 128, Mc / 128), 256, 0, stream>>>(xb, kwT, k_lin, Mc, QKDc, Dc, nullptr);
    zc_rms_kernel<QKDc><<<Mc, 256, 0, stream>>>(k_lin, k_scale);
    conv_silu<float><<<Mc, 256, 0, stream>>>(k_lin, k_conv_k, k_conv_b, kf, QKDc);

    // gate projection
    gemm_bt<bf16><<<dim3(Dc / 128, Mc / 128), 256, 0, stream>>>(xb, gwT, g_lin, Mc, Dc, Dc, nullptr);

    // alpha/beta
    alphabeta<<<Mc, 64, 0, stream>>>(x, alpha_w, beta_w, af, bfv);

    // DPP-based parallel delta-rule scan
    scan3<<<dim3(4, Bc * Hc), 256, 0, stream>>>(qf, kf, vc, af, bfv, o_core);

    // output projection with fused sigmoid gate -> fp32 d_out
    gemm_bt<float><<<dim3(Dc / 128, Mc / 128), 256, 0, stream>>>(o_core, owT, (float*)d_out, Mc, Dc, VDc, g_lin);
}

// Round 6
// 936.058 us; speedup vs baseline: 5.0610x; 1.0010x over previous
//
#include <hip/hip_runtime.h>

// ---------------- problem constants ----------------
#define Bc   4
#define Tc   2048
#define Dc   1024
#define Hc   16
#define DKc  64
#define DVc  128
#define QKDc 1024
#define VDc  2048
#define Mc   (Bc * Tc)   // 8192 tokens
#define SW   64          // scan LDS window (time steps)

typedef __bf16 bf16;
typedef __bf16 bf16x4 __attribute__((ext_vector_type(4)));
typedef __bf16 bf16x8 __attribute__((ext_vector_type(8)));
typedef float  f32x4  __attribute__((ext_vector_type(4)));

__device__ __forceinline__ float bf2f(bf16 v) { return (float)v; }
__device__ __forceinline__ bf16  f2bf(float v) { return (bf16)v; }
__device__ __forceinline__ float sigmoidf_(float x) { return 1.0f / (1.0f + __expf(-x)); }

// DPP-based add: x + lane_perm(x). VALU pipe (~4 cyc), not LDS pipe.
// 0xB1 = quad_perm xor-1, 0x4E = quad_perm xor-2,
// 0x141 = ROW_HALF_MIRROR (combines quads of each 8-group; HW-verified round 5),
// 0x140 = ROW_MIRROR (combines the two 8-halves of each 16-lane row).
template <int CTRL>
__device__ __forceinline__ float dpp_add(float x) {
    int xi = __float_as_int(x);
    int yi = __builtin_amdgcn_update_dpp(0, xi, CTRL, 0xF, 0xF, true);
    return x + __int_as_float(yi);
}
__device__ __forceinline__ float reduce16(float x) {
    x = dpp_add<0xB1>(x);
    x = dpp_add<0x4E>(x);
    x = dpp_add<0x141>(x);
    x = dpp_add<0x140>(x);
    return x;
}

// async global->LDS, 16B per lane; lds dest = wave-uniform base + lane*16
__device__ __forceinline__ void glds16(const bf16* g, void* l) {
    __builtin_amdgcn_global_load_lds((const __attribute__((address_space(1))) void*)g,
                                     (__attribute__((address_space(3))) void*)l, 16, 0, 0);
}

// ---------------- cast fp32 -> bf16 (vectorized) ----------------
__global__ __launch_bounds__(256) void cast_f32_bf16(const float* __restrict__ src,
                                                     bf16* __restrict__ dst, int n4) {
    int i = blockIdx.x * 256 + threadIdx.x;
    if (i < n4) {
        float4 v = ((const float4*)src)[i];
        bf16x4 o = { f2bf(v.x), f2bf(v.y), f2bf(v.z), f2bf(v.w) };
        ((bf16x4*)dst)[i] = o;
    }
}

// ---------------- transpose + cast: src fp32 [R][C] -> dst bf16 [C][R] ----------------
__global__ __launch_bounds__(256) void transpose_cast(const float* __restrict__ src,
                                                      bf16* __restrict__ dst,
                                                      int R, int C) {
    __shared__ float tile[32][33];
    int c0 = blockIdx.x * 32, r0 = blockIdx.y * 32;
    int tx = threadIdx.x, ty = threadIdx.y;  // block (32,8)
#pragma unroll
    for (int i = 0; i < 32; i += 8) {
        int r = r0 + ty + i, c = c0 + tx;
        tile[ty + i][tx] = (r < R && c < C) ? src[(size_t)r * C + c] : 0.0f;
    }
    __syncthreads();
#pragma unroll
    for (int i = 0; i < 32; i += 8) {
        int rr = c0 + ty + i, cc = r0 + tx;
        if (rr < C && cc < R) dst[(size_t)rr * R + cc] = f2bf(tile[tx][ty + i]);
    }
}

// ---------------- GEMM: C[M,N] = A[M,K] @ Bt[N,K]^T  (bf16 in, OutT out) ----------------
// m97 structure: async global_load_lds staging (16B/lane), 128x128 tile, BK=32.
template <typename OutT>
__global__ __launch_bounds__(256) void gemm_bt(const bf16* __restrict__ A,
                                               const bf16* __restrict__ Bt,
                                               OutT* __restrict__ C,
                                               int M, int N, int K,
                                               const bf16* __restrict__ gate) {
    __shared__ bf16 As[128 * 32];
    __shared__ bf16 Bs[128 * 32];

    const int n0 = blockIdx.x * 128;
    const int m0 = blockIdx.y * 128;
    const int t = threadIdx.x;
    const int wid = t >> 6, lane = t & 63;
    const int wm = (wid & 1) * 64;
    const int wn = (wid >> 1) * 64;

    f32x4 acc[4][4] = {};

    // staging: wave wid covers rows wid*16..+15 (and +64); lane -> (row, col8)
    const int srow = lane >> 2;          // 0..15
    const int scol = (lane & 3) * 8;     // bf16 col offset
    char* AsB = (char*)As;
    char* BsB = (char*)Bs;

    for (int k0 = 0; k0 < K; k0 += 32) {
        glds16(&A[(size_t)(m0 + wid * 16 + srow) * K + k0 + scol],       AsB + wid * 1024);
        glds16(&A[(size_t)(m0 + 64 + wid * 16 + srow) * K + k0 + scol],  AsB + 4096 + wid * 1024);
        glds16(&Bt[(size_t)(n0 + wid * 16 + srow) * K + k0 + scol],      BsB + wid * 1024);
        glds16(&Bt[(size_t)(n0 + 64 + wid * 16 + srow) * K + k0 + scol], BsB + 4096 + wid * 1024);
        __syncthreads();   // drains vmcnt (global_load_lds) before LDS reads

        const int kh = (lane >> 4) * 8;
        const int lm = lane & 15;
        bf16x8 a[4], b[4];
#pragma unroll
        for (int i = 0; i < 4; i++) a[i] = *(const bf16x8*)&As[(wm + i * 16 + lm) * 32 + kh];
#pragma unroll
        for (int j = 0; j < 4; j++) b[j] = *(const bf16x8*)&Bs[(wn + j * 16 + lm) * 32 + kh];
#pragma unroll
        for (int i = 0; i < 4; i++)
#pragma unroll
            for (int j = 0; j < 4; j++)
                acc[i][j] = __builtin_amdgcn_mfma_f32_16x16x32_bf16(a[i], b[j], acc[i][j], 0, 0, 0);
        __syncthreads();
    }

    const int lm = lane & 15, lq = lane >> 4;
#pragma unroll
    for (int i = 0; i < 4; i++) {
#pragma unroll
        for (int j = 0; j < 4; j++) {
#pragma unroll
            for (int rI = 0; rI < 4; rI++) {
                int row = m0 + wm + i * 16 + lq * 4 + rI;
                int col = n0 + wn + j * 16 + lm;
                float val = acc[i][j][rI];
                if (gate) {
                    float g = bf2f(gate[(size_t)row * N + col]);
                    val *= sigmoidf_(g);
                }
                C[(size_t)row * N + col] = (OutT)val;
            }
        }
    }
}

// ---------------- zero-centered RMSNorm (in place on bf16, one block per row) ----------------
template <int L>
__global__ __launch_bounds__(256) void zc_rms_kernel(bf16* __restrict__ buf,
                                                     const float* __restrict__ scale) {
    constexpr int NPT = L / 256;
    int row = blockIdx.x;
    int t = threadIdx.x;
    bf16* p = buf + (size_t)row * L;

    float xv[NPT];
    float s = 0.f, s2 = 0.f;
#pragma unroll
    for (int i = 0; i < NPT; i++) {
        float x = bf2f(p[t + (i << 8)]);
        xv[i] = x;
        s += x;
        s2 += x * x;
    }
    __shared__ float red[2][4];
#pragma unroll
    for (int o = 32; o > 0; o >>= 1) {
        s += __shfl_down(s, o, 64);
        s2 += __shfl_down(s2, o, 64);
    }
    if ((t & 63) == 0) { red[0][t >> 6] = s; red[1][t >> 6] = s2; }
    __syncthreads();
    s  = red[0][0] + red[0][1] + red[0][2] + red[0][3];
    s2 = red[1][0] + red[1][1] + red[1][2] + red[1][3];

    float mean = s / (float)L;
    float var = s2 / (float)L - mean * mean;
    float inv = rsqrtf(var + 1e-5f);
#pragma unroll
    for (int i = 0; i < NPT; i++) {
        float y = (xv[i] - mean) * inv * scale[t + (i << 8)];
        p[t + (i << 8)] = f2bf(y);
    }
}

// ---------------- causal depthwise conv (K=4) + SiLU, bf16 in -> OutT out ----------------
template <typename OutT>
__global__ __launch_bounds__(256) void conv_silu(const bf16* __restrict__ xn,
                                                 const float* __restrict__ kern,
                                                 const float* __restrict__ bias,
                                                 OutT* __restrict__ out, int Cch) {
    int btok = blockIdx.x;
    int tt = btok & (Tc - 1);
    for (int c = threadIdx.x; c < Cch; c += 256) {
        float acc = bias[c];
#pragma unroll
        for (int i = 0; i < 4; i++) {
            int ts = tt - 3 + i;
            if (ts >= 0)
                acc += bf2f(xn[(size_t)(btok - 3 + i) * Cch + c]) * kern[i * Cch + c];
        }
        float y = acc * sigmoidf_(acc);
        out[(size_t)btok * Cch + c] = (OutT)y;
    }
}

// ---------------- alpha / beta: sigmoid(x @ W) for W [D,16], fp32 in ----------------
__global__ __launch_bounds__(64) void alphabeta(const float* __restrict__ x,
                                                const float* __restrict__ aw,
                                                const float* __restrict__ bw,
                                                float* __restrict__ af,
                                                float* __restrict__ bfv) {
    int tok = blockIdx.x;
    int lane = threadIdx.x;
    const float* xr = x + (size_t)tok * Dc;
    float accA[16] = {};
    float accB[16] = {};
    for (int k = lane; k < Dc; k += 64) {
        float xv = xr[k];
        const float* awr = aw + (size_t)k * Hc;
        const float* bwr = bw + (size_t)k * Hc;
#pragma unroll
        for (int h = 0; h < 16; h++) {
            accA[h] += xv * awr[h];
            accB[h] += xv * bwr[h];
        }
    }
#pragma unroll
    for (int h = 0; h < 16; h++) {
        float a = accA[h], b = accB[h];
#pragma unroll
        for (int o = 32; o > 0; o >>= 1) {
            a += __shfl_down(a, o, 64);
            b += __shfl_down(b, o, 64);
        }
        if (lane == 0) {
            af[(size_t)tok * Hc + h] = sigmoidf_(a);
            bfv[(size_t)tok * Hc + h] = sigmoidf_(b);
        }
    }
}

// ---------------- gated delta-rule scan, v4: 16-lane split, 512 blocks ----------------
// grid = (8 vgroups, 64 bh), 256 threads. dgrp = lane&15 owns d = dgrp*4..+3,
// column = wave*4 + lane>>4 (4 cols/wave, 16 cols/block). reduce16 via 4 DPP stages.
// LDS ~75 KB -> 2 blocks/CU (vs scan3's 87 KB / 1 block) => 2 waves/SIMD latency hiding.
__global__ __launch_bounds__(256) void scan4(const float* __restrict__ qf,
                                             const float* __restrict__ kf,
                                             const bf16* __restrict__ vc,
                                             const float* __restrict__ af,
                                             const float* __restrict__ bfv,
                                             bf16* __restrict__ o) {
    const int vg = blockIdx.x;                 // 0..7
    const int bh = blockIdx.y;                 // 0..63
    const int b = bh >> 4, h = bh & 15;
    const int tid = threadIdx.x;
    const int wave = tid >> 6, lane = tid & 63;
    const int dgrp = lane & 15;                // d-range dgrp*4..+3
    const int vloc = wave * 4 + (lane >> 4);   // 0..15 column within block

    __shared__ float k_lds[2][SW][64];         // 32 KB
    __shared__ float q_lds[2][SW][64];         // 32 KB
    __shared__ float v_lds[2][SW][16];         //  8 KB
    __shared__ float a_lds[2][SW];
    __shared__ float b_lds[2][SW];
    __shared__ bf16  o_tile[SW][16];           //  2 KB

    const size_t base_kq = ((size_t)b * Tc) * QKDc + (size_t)h * DKc;
    const size_t base_v  = ((size_t)b * Tc) * VDc + (size_t)h * DVc + (size_t)vg * 16;
    const size_t base_ab = ((size_t)b * Tc) * Hc + h;

    float S[4];
#pragma unroll
    for (int j = 0; j < 4; j++) S[j] = 0.f;

    f32x4 kr[4], qr[4];
    bf16x4 vr;
    float abr = 0.f;

    auto stage_load = [&](int t0) {
#pragma unroll
        for (int i = 0; i < 4; i++) {
            int c = tid + i * 256;             // f32x4 chunk id, 16 chunks/row
            int row = c >> 4, colb = (c & 15) * 4;
            kr[i] = *(const f32x4*)&kf[base_kq + (size_t)(t0 + row) * QKDc + colb];
            qr[i] = *(const f32x4*)&qf[base_kq + (size_t)(t0 + row) * QKDc + colb];
        }
        {
            int row = tid >> 2, colb = (tid & 3) * 4;
            vr = *(const bf16x4*)&vc[base_v + (size_t)(t0 + row) * VDc + colb];
        }
        if (tid < SW) abr = af[base_ab + (size_t)(t0 + tid) * Hc];
        else if (tid < 2 * SW) abr = bfv[base_ab + (size_t)(t0 + tid - SW) * Hc];
    };

    auto stage_write = [&](int buf) {
#pragma unroll
        for (int i = 0; i < 4; i++) {
            int c = tid + i * 256;
            int row = c >> 4, colb = (c & 15) * 4;
            *(f32x4*)&k_lds[buf][row][colb] = kr[i];
            *(f32x4*)&q_lds[buf][row][colb] = qr[i];
        }
        {
            int row = tid >> 2, colb = (tid & 3) * 4;
            f32x4 vv = { bf2f(vr[0]), bf2f(vr[1]), bf2f(vr[2]), bf2f(vr[3]) };
            *(f32x4*)&v_lds[buf][row][colb] = vv;
        }
        if (tid < SW) a_lds[buf][tid] = abr;
        else if (tid < 2 * SW) b_lds[buf][tid - SW] = abr;
    };

    stage_load(0);
    stage_write(0);
    __syncthreads();

    const int nwin = Tc / SW;   // 32
    for (int w = 0; w < nwin; w++) {
        const int buf = w & 1;
        if (w + 1 < nwin) stage_load((w + 1) * SW);   // overlap HBM with compute

#pragma unroll 4
        for (int t = 0; t < SW; t++) {
            f32x4 kk = *(const f32x4*)&k_lds[buf][t][dgrp * 4];
            f32x4 qq = *(const f32x4*)&q_lds[buf][t][dgrp * 4];
            float a  = a_lds[buf][t];
            float bb = b_lds[buf][t];
            float vv = v_lds[buf][t][vloc];

            float pA = kk[0] * S[0] + kk[2] * S[2];
            float pB = kk[1] * S[1] + kk[3] * S[3];
            float p = reduce16(pA + pB);       // VALU-pipe 16-lane sum

            float delta = bb * (vv - a * p);

            float oA = 0.f, oB = 0.f;
#pragma unroll
            for (int j = 0; j < 4; j++) {
                float s = a * S[j] + delta * kk[j];
                S[j] = s;
                if (j & 1) oB += qq[j] * s; else oA += qq[j] * s;
            }
            float oo = reduce16(oA + oB);
            if (dgrp == 0) o_tile[t][vloc] = f2bf(oo);
        }
        __syncthreads();   // o_tile complete; current buf free for rewrite

        {   // flush o_tile (4 bf16 = 8 B per thread, coalesced)
            int row = tid >> 2, colb = (tid & 3) * 4;
            *(uint2*)&o[base_v + (size_t)(w * SW + row) * VDc + colb] =
                *(const uint2*)&o_tile[row][colb];
        }
        if (w + 1 < nwin) stage_write((w + 1) & 1);
        __syncthreads();
    }
}

// ---------------- host launch ----------------
extern "C" void kernel_launch(void* const* d_in, const int* in_sizes, int n_in,
                              void* d_out, int out_size, void* d_ws, size_t ws_size,
                              hipStream_t stream) {
    const float* x        = (const float*)d_in[0];
    const float* q_w      = (const float*)d_in[1];
    const float* k_w      = (const float*)d_in[2];
    const float* v_w      = (const float*)d_in[3];
    const float* q_scale  = (const float*)d_in[4];
    const float* k_scale  = (const float*)d_in[5];
    const float* v_scale  = (const float*)d_in[6];
    const float* q_conv_k = (const float*)d_in[7];
    const float* q_conv_b = (const float*)d_in[8];
    const float* k_conv_k = (const float*)d_in[9];
    const float* k_conv_b = (const float*)d_in[10];
    const float* v_conv_k = (const float*)d_in[11];
    const float* v_conv_b = (const float*)d_in[12];
    const float* alpha_w  = (const float*)d_in[13];
    const float* beta_w   = (const float*)d_in[14];
    const float* out_w    = (const float*)d_in[15];
    const float* gate_w   = (const float*)d_in[16];

    char* w = (char*)d_ws;
    bf16* xb  = (bf16*)w; w += (size_t)Mc * Dc * 2;
    bf16* qwT = (bf16*)w; w += (size_t)QKDc * Dc * 2;
    bf16* kwT = (bf16*)w; w += (size_t)QKDc * Dc * 2;
    bf16* vwT = (bf16*)w; w += (size_t)VDc * Dc * 2;
    bf16* gwT = (bf16*)w; w += (size_t)Dc * Dc * 2;
    bf16* owT = (bf16*)w; w += (size_t)Dc * VDc * 2;
    bf16* q_lin = (bf16*)w; w += (size_t)Mc * QKDc * 2;
    bf16* k_lin = (bf16*)w; w += (size_t)Mc * QKDc * 2;
    bf16* v_lin = (bf16*)w; w += (size_t)Mc * VDc * 2;
    bf16* g_lin = (bf16*)w; w += (size_t)Mc * Dc * 2;
    bf16* vc  = (bf16*)w; w += (size_t)Mc * VDc * 2;
    float* kf = (float*)w; w += (size_t)Mc * QKDc * 4;
    float* af = (float*)w; w += (size_t)Mc * Hc * 4;
    float* bfv = (float*)w; w += (size_t)Mc * Hc * 4;
    float* qf = (float*)v_lin;       // alias: v_lin dead after conv v
    bf16* o_core = q_lin;            // alias: q_lin+k_lin dead after convs

    dim3 tb(32, 8);
    cast_f32_bf16<<<(Mc * Dc / 4 + 255) / 256, 256, 0, stream>>>(x, xb, Mc * Dc / 4);
    transpose_cast<<<dim3(QKDc / 32, Dc / 32), tb, 0, stream>>>(q_w, qwT, Dc, QKDc);
    transpose_cast<<<dim3(QKDc / 32, Dc / 32), tb, 0, stream>>>(k_w, kwT, Dc, QKDc);
    transpose_cast<<<dim3(VDc / 32, Dc / 32), tb, 0, stream>>>(v_w, vwT, Dc, VDc);
    transpose_cast<<<dim3(Dc / 32, Dc / 32), tb, 0, stream>>>(gate_w, gwT, Dc, Dc);
    transpose_cast<<<dim3(Dc / 32, VDc / 32), tb, 0, stream>>>(out_w, owT, VDc, Dc);

    // V pipeline first (v_lin dies before qf aliases it)
    gemm_bt<bf16><<<dim3(VDc / 128, Mc / 128), 256, 0, stream>>>(xb, vwT, v_lin, Mc, VDc, Dc, nullptr);
    zc_rms_kernel<VDc><<<Mc, 256, 0, stream>>>(v_lin, v_scale);
    conv_silu<bf16><<<Mc, 256, 0, stream>>>(v_lin, v_conv_k, v_conv_b, vc, VDc);

    // Q pipeline (qf overwrites v_lin)
    gemm_bt<bf16><<<dim3(QKDc / 128, Mc / 128), 256, 0, stream>>>(xb, qwT, q_lin, Mc, QKDc, Dc, nullptr);
    zc_rms_kernel<QKDc><<<Mc, 256, 0, stream>>>(q_lin, q_scale);
    conv_silu<float><<<Mc, 256, 0, stream>>>(q_lin, q_conv_k, q_conv_b, qf, QKDc);

    // K pipeline
    gemm_bt<bf16><<<dim3(QKDc / 128, Mc / 128), 256, 0, stream>>>(xb, kwT, k_lin, Mc, QKDc, Dc, nullptr);
    zc_rms_kernel<QKDc><<<Mc, 256, 0, stream>>>(k_lin, k_scale);
    conv_silu<float><<<Mc, 256, 0, stream>>>(k_lin, k_conv_k, k_conv_b, kf, QKDc);

    // gate projection
    gemm_bt<bf16><<<dim3(Dc / 128, Mc / 128), 256, 0, stream>>>(xb, gwT, g_lin, Mc, Dc, Dc, nullptr);

    // alpha/beta
    alphabeta<<<Mc, 64, 0, stream>>>(x, alpha_w, beta_w, af, bfv);

    // 16-lane-split DPP delta-rule scan
    scan4<<<dim3(8, Bc * Hc), 256, 0, stream>>>(qf, kf, vc, af, bfv, o_core);

    // output projection with fused sigmoid gate -> fp32 d_out
    gemm_bt<float><<<dim3(Dc / 128, Mc / 128), 256, 0, stream>>>(o_core, owT, (float*)d_out, Mc, Dc, VDc, g_lin);
}

// Round 7
// 916.569 us; speedup vs baseline: 5.1686x; 1.0213x over previous
//
#include <hip/hip_runtime.h>

// ---------------- problem constants ----------------
#define Bc   4
#define Tc   2048
#define Dc   1024
#define Hc   16
#define DKc  64
#define DVc  128
#define QKDc 1024
#define VDc  2048
#define NPRJ 5120        // q|k|v|gate fused projection width
#define Mc   (Bc * Tc)   // 8192 tokens
#define SW   64          // scan LDS window (time steps)

typedef __bf16 bf16;
typedef __bf16 bf16x4 __attribute__((ext_vector_type(4)));
typedef __bf16 bf16x8 __attribute__((ext_vector_type(8)));
typedef float  f32x4  __attribute__((ext_vector_type(4)));

__device__ __forceinline__ float bf2f(bf16 v) { return (float)v; }
__device__ __forceinline__ bf16  f2bf(float v) { return (bf16)v; }
__device__ __forceinline__ float sigmoidf_(float x) { return 1.0f / (1.0f + __expf(-x)); }

// DPP adds (VALU pipe). 0xB1=quad_perm xor1, 0x4E=quad_perm xor2,
// 0x141=ROW_HALF_MIRROR. reduce8 sums each aligned 8-lane group (HW-verified r5).
template <int CTRL>
__device__ __forceinline__ float dpp_add(float x) {
    int xi = __float_as_int(x);
    int yi = __builtin_amdgcn_update_dpp(0, xi, CTRL, 0xF, 0xF, true);
    return x + __int_as_float(yi);
}
__device__ __forceinline__ float reduce8(float x) {
    x = dpp_add<0xB1>(x);
    x = dpp_add<0x4E>(x);
    x = dpp_add<0x141>(x);
    return x;
}

// async global->LDS, 16B/lane; lds dest = wave-uniform base + lane*16
__device__ __forceinline__ void glds16(const bf16* g, void* l) {
    __builtin_amdgcn_global_load_lds((const __attribute__((address_space(1))) void*)g,
                                     (__attribute__((address_space(3))) void*)l, 16, 0, 0);
}

// ---------------- cast fp32 -> bf16 ----------------
__global__ __launch_bounds__(256) void cast_f32_bf16(const float* __restrict__ src,
                                                     bf16* __restrict__ dst, int n4) {
    int i = blockIdx.x * 256 + threadIdx.x;
    if (i < n4) {
        float4 v = ((const float4*)src)[i];
        bf16x4 o = { f2bf(v.x), f2bf(v.y), f2bf(v.z), f2bf(v.w) };
        ((bf16x4*)dst)[i] = o;
    }
}

// ---------------- transpose + cast: fp32 [R][C] -> bf16 [C][R] ----------------
__global__ __launch_bounds__(256) void transpose_cast(const float* __restrict__ src,
                                                      bf16* __restrict__ dst,
                                                      int R, int C) {
    __shared__ float tile[32][33];
    int c0 = blockIdx.x * 32, r0 = blockIdx.y * 32;
    int tx = threadIdx.x, ty = threadIdx.y;
#pragma unroll
    for (int i = 0; i < 32; i += 8) {
        int r = r0 + ty + i, c = c0 + tx;
        tile[ty + i][tx] = (r < R && c < C) ? src[(size_t)r * C + c] : 0.0f;
    }
    __syncthreads();
#pragma unroll
    for (int i = 0; i < 32; i += 8) {
        int rr = c0 + ty + i, cc = r0 + tx;
        if (rr < C && cc < R) dst[(size_t)rr * R + cc] = f2bf(tile[tx][ty + i]);
    }
}

// ---------------- GEMM: C[M,N] = A[M,K] @ Bt[N,K]^T, strided A/C/gate ----------------
template <typename OutT>
__global__ __launch_bounds__(256) void gemm_bt(const bf16* __restrict__ A,
                                               const bf16* __restrict__ Bt,
                                               OutT* __restrict__ C,
                                               int M, int N, int K,
                                               const bf16* __restrict__ gate,
                                               int lda, int ldc, int ldg) {
    __shared__ bf16 As[128 * 32];
    __shared__ bf16 Bs[128 * 32];

    const int n0 = blockIdx.x * 128;
    const int m0 = blockIdx.y * 128;
    const int t = threadIdx.x;
    const int wid = t >> 6, lane = t & 63;
    const int wm = (wid & 1) * 64;
    const int wn = (wid >> 1) * 64;

    f32x4 acc[4][4] = {};

    const int srow = lane >> 2;          // 0..15
    const int scol = (lane & 3) * 8;     // bf16 col offset
    char* AsB = (char*)As;
    char* BsB = (char*)Bs;

    for (int k0 = 0; k0 < K; k0 += 32) {
        glds16(&A[(size_t)(m0 + wid * 16 + srow) * lda + k0 + scol],       AsB + wid * 1024);
        glds16(&A[(size_t)(m0 + 64 + wid * 16 + srow) * lda + k0 + scol],  AsB + 4096 + wid * 1024);
        glds16(&Bt[(size_t)(n0 + wid * 16 + srow) * K + k0 + scol],        BsB + wid * 1024);
        glds16(&Bt[(size_t)(n0 + 64 + wid * 16 + srow) * K + k0 + scol],   BsB + 4096 + wid * 1024);
        __syncthreads();

        const int kh = (lane >> 4) * 8;
        const int lm = lane & 15;
        bf16x8 a[4], b[4];
#pragma unroll
        for (int i = 0; i < 4; i++) a[i] = *(const bf16x8*)&As[(wm + i * 16 + lm) * 32 + kh];
#pragma unroll
        for (int j = 0; j < 4; j++) b[j] = *(const bf16x8*)&Bs[(wn + j * 16 + lm) * 32 + kh];
#pragma unroll
        for (int i = 0; i < 4; i++)
#pragma unroll
            for (int j = 0; j < 4; j++)
                acc[i][j] = __builtin_amdgcn_mfma_f32_16x16x32_bf16(a[i], b[j], acc[i][j], 0, 0, 0);
        __syncthreads();
    }

    const int lm = lane & 15, lq = lane >> 4;
#pragma unroll
    for (int i = 0; i < 4; i++) {
#pragma unroll
        for (int j = 0; j < 4; j++) {
#pragma unroll
            for (int rI = 0; rI < 4; rI++) {
                int row = m0 + wm + i * 16 + lq * 4 + rI;
                int col = n0 + wn + j * 16 + lm;
                float val = acc[i][j][rI];
                if (gate) {
                    float g = bf2f(gate[(size_t)row * ldg + col]);
                    val *= sigmoidf_(g);
                }
                C[(size_t)row * ldc + col] = (OutT)val;
            }
        }
    }
}

// ---------------- zero-centered RMSNorm in place, strided rows ----------------
template <int L>
__global__ __launch_bounds__(256) void zc_rms_kernel(bf16* __restrict__ buf,
                                                     const float* __restrict__ scale,
                                                     int ld) {
    constexpr int NPT = L / 256;
    int row = blockIdx.x;
    int t = threadIdx.x;
    bf16* p = buf + (size_t)row * ld;

    float xv[NPT];
    float s = 0.f, s2 = 0.f;
#pragma unroll
    for (int i = 0; i < NPT; i++) {
        float x = bf2f(p[t + (i << 8)]);
        xv[i] = x;
        s += x;
        s2 += x * x;
    }
    __shared__ float red[2][4];
#pragma unroll
    for (int o = 32; o > 0; o >>= 1) {
        s += __shfl_down(s, o, 64);
        s2 += __shfl_down(s2, o, 64);
    }
    if ((t & 63) == 0) { red[0][t >> 6] = s; red[1][t >> 6] = s2; }
    __syncthreads();
    s  = red[0][0] + red[0][1] + red[0][2] + red[0][3];
    s2 = red[1][0] + red[1][1] + red[1][2] + red[1][3];

    float mean = s / (float)L;
    float var = s2 / (float)L - mean * mean;
    float inv = rsqrtf(var + 1e-5f);
#pragma unroll
    for (int i = 0; i < NPT; i++) {
        float y = (xv[i] - mean) * inv * scale[t + (i << 8)];
        p[t + (i << 8)] = f2bf(y);
    }
}

// ---------------- causal depthwise conv (K=4) + SiLU, strided in, compact out ----------------
__global__ __launch_bounds__(256) void conv_silu(const bf16* __restrict__ xn,
                                                 const float* __restrict__ kern,
                                                 const float* __restrict__ bias,
                                                 bf16* __restrict__ out,
                                                 int Cch, int ldin) {
    int btok = blockIdx.x;
    int tt = btok & (Tc - 1);
    for (int c = threadIdx.x; c < Cch; c += 256) {
        float acc = bias[c];
#pragma unroll
        for (int i = 0; i < 4; i++) {
            int ts = tt - 3 + i;
            if (ts >= 0)
                acc += bf2f(xn[(size_t)(btok - 3 + i) * ldin + c]) * kern[i * Cch + c];
        }
        float y = acc * sigmoidf_(acc);
        out[(size_t)btok * Cch + c] = f2bf(y);
    }
}

// ---------------- alpha / beta: sigmoid(x @ W) for W [D,16], bf16 x ----------------
__global__ __launch_bounds__(64) void alphabeta(const bf16* __restrict__ x,
                                                const float* __restrict__ aw,
                                                const float* __restrict__ bw,
                                                float* __restrict__ af,
                                                float* __restrict__ bfv) {
    int tok = blockIdx.x;
    int lane = threadIdx.x;
    const bf16* xr = x + (size_t)tok * Dc;
    float accA[16] = {};
    float accB[16] = {};
    for (int k = lane; k < Dc; k += 64) {
        float xv = bf2f(xr[k]);
        const float* awr = aw + (size_t)k * Hc;
        const float* bwr = bw + (size_t)k * Hc;
#pragma unroll
        for (int h = 0; h < 16; h++) {
            accA[h] += xv * awr[h];
            accB[h] += xv * bwr[h];
        }
    }
#pragma unroll
    for (int h = 0; h < 16; h++) {
        float a = accA[h], b = accB[h];
#pragma unroll
        for (int o = 32; o > 0; o >>= 1) {
            a += __shfl_down(a, o, 64);
            b += __shfl_down(b, o, 64);
        }
        if (lane == 0) {
            af[(size_t)tok * Hc + h] = sigmoidf_(a);
            bfv[(size_t)tok * Hc + h] = sigmoidf_(b);
        }
    }
}

// ---------------- gated delta-rule scan, v5: bf16 LDS, 8-lane split ----------------
// grid = (4 vgroups, 64 bh), 256 threads, 1 block/CU. dgrp = lane&7 owns
// d = dgrp*8..+7; vloc = wave*8 + lane>>3 (32 cols/block). k/q/v staged in LDS
// as bf16 (round-6 lesson: scan is LDS-instruction bound — bf16 halves b128
// count per wave-step: 2×b128 + 3 scalars ≈ 41 cyc vs scan3's 65 / scan4's 8×41).
__global__ __launch_bounds__(256) void scan5(const bf16* __restrict__ qf,
                                             const bf16* __restrict__ kf,
                                             const bf16* __restrict__ vc,
                                             const float* __restrict__ af,
                                             const float* __restrict__ bfv,
                                             bf16* __restrict__ o, int ldo) {
    const int vg = blockIdx.x;                 // 0..3
    const int bh = blockIdx.y;                 // 0..63
    const int b = bh >> 4, h = bh & 15;
    const int tid = threadIdx.x;
    const int wave = tid >> 6, lane = tid & 63;
    const int dgrp = lane & 7;
    const int vloc = wave * 8 + (lane >> 3);   // 0..31

    __shared__ bf16  k_lds[2][SW][64];         // 16 KB
    __shared__ bf16  q_lds[2][SW][64];         // 16 KB
    __shared__ bf16  v_lds[2][SW][32];         //  8 KB
    __shared__ float a_lds[2][SW];
    __shared__ float b_lds[2][SW];
    __shared__ bf16  o_tile[SW][32];           //  4 KB

    const size_t base_kq = ((size_t)b * Tc) * QKDc + (size_t)h * DKc;
    const size_t base_v  = ((size_t)b * Tc) * VDc + (size_t)h * DVc + (size_t)vg * 32;
    const size_t base_o  = (size_t)h * DVc + (size_t)vg * 32;   // col offset in o
    const size_t base_ab = ((size_t)b * Tc) * Hc + h;

    float S[8];
#pragma unroll
    for (int j = 0; j < 8; j++) S[j] = 0.f;

    bf16x8 kr[2], qr[2], vr;
    float abr = 0.f;

    // k/q: 512 16B-chunks per window (8/row); v: 256 chunks (4/row)
    auto stage_load = [&](int t0) {
#pragma unroll
        for (int i = 0; i < 2; i++) {
            int c = tid + i * 256;
            int row = c >> 3, col8 = (c & 7) * 8;
            kr[i] = *(const bf16x8*)&kf[base_kq + (size_t)(t0 + row) * QKDc + col8];
            qr[i] = *(const bf16x8*)&qf[base_kq + (size_t)(t0 + row) * QKDc + col8];
        }
        {
            int row = tid >> 2, col8 = (tid & 3) * 8;
            vr = *(const bf16x8*)&vc[base_v + (size_t)(t0 + row) * VDc + col8];
        }
        if (tid < SW) abr = af[base_ab + (size_t)(t0 + tid) * Hc];
        else if (tid < 2 * SW) abr = bfv[base_ab + (size_t)(t0 + tid - SW) * Hc];
    };

    auto stage_write = [&](int buf) {
#pragma unroll
        for (int i = 0; i < 2; i++) {
            int c = tid + i * 256;
            int row = c >> 3, col8 = (c & 7) * 8;
            *(bf16x8*)&k_lds[buf][row][col8] = kr[i];
            *(bf16x8*)&q_lds[buf][row][col8] = qr[i];
        }
        {
            int row = tid >> 2, col8 = (tid & 3) * 8;
            *(bf16x8*)&v_lds[buf][row][col8] = vr;
        }
        if (tid < SW) a_lds[buf][tid] = abr;
        else if (tid < 2 * SW) b_lds[buf][tid - SW] = abr;
    };

    stage_load(0);
    stage_write(0);
    __syncthreads();

    const int nwin = Tc / SW;   // 32
    for (int w = 0; w < nwin; w++) {
        const int buf = w & 1;
        if (w + 1 < nwin) stage_load((w + 1) * SW);

#pragma unroll 4
        for (int t = 0; t < SW; t++) {
            bf16x8 kk = *(const bf16x8*)&k_lds[buf][t][dgrp * 8];
            bf16x8 qq = *(const bf16x8*)&q_lds[buf][t][dgrp * 8];
            float a  = a_lds[buf][t];
            float bb = b_lds[buf][t];
            float vv = bf2f(v_lds[buf][t][vloc]);

            float kfl[8], qfl[8];
#pragma unroll
            for (int j = 0; j < 8; j++) { kfl[j] = bf2f(kk[j]); qfl[j] = bf2f(qq[j]); }

            float pA = kfl[0] * S[0] + kfl[2] * S[2] + kfl[4] * S[4] + kfl[6] * S[6];
            float pB = kfl[1] * S[1] + kfl[3] * S[3] + kfl[5] * S[5] + kfl[7] * S[7];
            float p = reduce8(pA + pB);

            float delta = bb * (vv - a * p);

            float oA = 0.f, oB = 0.f;
#pragma unroll
            for (int j = 0; j < 8; j++) {
                float s = a * S[j] + delta * kfl[j];
                S[j] = s;
                if (j & 1) oB += qfl[j] * s; else oA += qfl[j] * s;
            }
            float oo = reduce8(oA + oB);
            if (dgrp == 0) o_tile[t][vloc] = f2bf(oo);
        }
        __syncthreads();

        {   // flush o_tile: 256 chunks of 16B, strided output rows
            int row = tid >> 2, col8 = (tid & 3) * 8;
            *(uint4*)&o[(size_t)(b * Tc + w * SW + row) * ldo + base_o + col8] =
                *(const uint4*)&o_tile[row][col8];
        }
        if (w + 1 < nwin) stage_write((w + 1) & 1);
        __syncthreads();
    }
}

// ---------------- host launch ----------------
extern "C" void kernel_launch(void* const* d_in, const int* in_sizes, int n_in,
                              void* d_out, int out_size, void* d_ws, size_t ws_size,
                              hipStream_t stream) {
    const float* x        = (const float*)d_in[0];
    const float* q_w      = (const float*)d_in[1];
    const float* k_w      = (const float*)d_in[2];
    const float* v_w      = (const float*)d_in[3];
    const float* q_scale  = (const float*)d_in[4];
    const float* k_scale  = (const float*)d_in[5];
    const float* v_scale  = (const float*)d_in[6];
    const float* q_conv_k = (const float*)d_in[7];
    const float* q_conv_b = (const float*)d_in[8];
    const float* k_conv_k = (const float*)d_in[9];
    const float* k_conv_b = (const float*)d_in[10];
    const float* v_conv_k = (const float*)d_in[11];
    const float* v_conv_b = (const float*)d_in[12];
    const float* alpha_w  = (const float*)d_in[13];
    const float* beta_w   = (const float*)d_in[14];
    const float* out_w    = (const float*)d_in[15];
    const float* gate_w   = (const float*)d_in[16];

    // ---- workspace (~175 MB) ----
    char* w = (char*)d_ws;
    bf16* xb  = (bf16*)w; w += (size_t)Mc * Dc * 2;          // 16 MB
    bf16* qwT = (bf16*)w; w += (size_t)QKDc * Dc * 2;        //  2 MB  -- qwT|kwT|vwT|gwT
    bf16* kwT = (bf16*)w; w += (size_t)QKDc * Dc * 2;        //  2 MB     contiguous =
    bf16* vwT = (bf16*)w; w += (size_t)VDc * Dc * 2;         //  4 MB     [5120][1024]
    bf16* gwT = (bf16*)w; w += (size_t)Dc * Dc * 2;          //  2 MB
    bf16* owT = (bf16*)w; w += (size_t)Dc * VDc * 2;         //  4 MB
    bf16* lin_all = (bf16*)w; w += (size_t)Mc * NPRJ * 2;    // 80 MB  [M][5120] q|k|v|g
    bf16* qf = (bf16*)w; w += (size_t)Mc * QKDc * 2;         // 16 MB
    bf16* kf = (bf16*)w; w += (size_t)Mc * QKDc * 2;         // 16 MB
    bf16* vc = (bf16*)w; w += (size_t)Mc * VDc * 2;          // 32 MB
    float* af = (float*)w; w += (size_t)Mc * Hc * 4;
    float* bfv = (float*)w; w += (size_t)Mc * Hc * 4;
    // scan output goes into lin_all cols 0:2048 (q|k sections, dead after convs)
    bf16* o_core = lin_all;

    dim3 tb(32, 8);
    cast_f32_bf16<<<(Mc * Dc / 4 + 255) / 256, 256, 0, stream>>>(x, xb, Mc * Dc / 4);
    transpose_cast<<<dim3(QKDc / 32, Dc / 32), tb, 0, stream>>>(q_w, qwT, Dc, QKDc);
    transpose_cast<<<dim3(QKDc / 32, Dc / 32), tb, 0, stream>>>(k_w, kwT, Dc, QKDc);
    transpose_cast<<<dim3(VDc / 32, Dc / 32), tb, 0, stream>>>(v_w, vwT, Dc, VDc);
    transpose_cast<<<dim3(Dc / 32, Dc / 32), tb, 0, stream>>>(gate_w, gwT, Dc, Dc);
    transpose_cast<<<dim3(Dc / 32, VDc / 32), tb, 0, stream>>>(out_w, owT, VDc, Dc);

    // fused q|k|v|gate projection: one 8192x5120x1024 GEMM (xb fetched once)
    gemm_bt<bf16><<<dim3(NPRJ / 128, Mc / 128), 256, 0, stream>>>(
        xb, qwT, lin_all, Mc, NPRJ, Dc, nullptr, Dc, NPRJ, 0);

    // norms (strided rows inside lin_all)
    zc_rms_kernel<QKDc><<<Mc, 256, 0, stream>>>(lin_all,        q_scale, NPRJ);
    zc_rms_kernel<QKDc><<<Mc, 256, 0, stream>>>(lin_all + 1024, k_scale, NPRJ);
    zc_rms_kernel<VDc><<<Mc, 256, 0, stream>>>(lin_all + 2048,  v_scale, NPRJ);

    // convs: strided in, compact bf16 out
    conv_silu<<<Mc, 256, 0, stream>>>(lin_all,        q_conv_k, q_conv_b, qf, QKDc, NPRJ);
    conv_silu<<<Mc, 256, 0, stream>>>(lin_all + 1024, k_conv_k, k_conv_b, kf, QKDc, NPRJ);
    conv_silu<<<Mc, 256, 0, stream>>>(lin_all + 2048, v_conv_k, v_conv_b, vc, VDc, NPRJ);

    alphabeta<<<Mc, 64, 0, stream>>>(xb, alpha_w, beta_w, af, bfv);

    // bf16-LDS delta-rule scan; output strided into lin_all cols 0:2048
    scan5<<<dim3(4, Bc * Hc), 256, 0, stream>>>(qf, kf, vc, af, bfv, o_core, NPRJ);

    // out-projection (A = o_core strided in lin_all) + fused sigmoid gate (cols 4096:5120)
    gemm_bt<float><<<dim3(Dc / 128, Mc / 128), 256, 0, stream>>>(
        o_core, owT, (float*)d_out, Mc, Dc, VDc, lin_all + 4096, NPRJ, Dc, NPRJ);
}